// Round 2
// baseline (984.596 us; speedup 1.0000x reference)
//
#include <hip/hip_runtime.h>

#define B_  8
#define C_  512
#define NN_ 19
#define HW_ 16384

// ---- workspace layout (float offsets) ----
#define E_OFF   0ul        // [B][19][HW] exp(scores)        2,490,368 f
#define L_OFF   2490368ul  // [B][19] softmax denominators         152 f (pad to 256)
#define OCR_OFF 2490624ul  // [B][19][C] unnormalized ocr       77,824 f
#define CTX_OFF 2568448ul  // [B][C]                             4,096 f
#define T1_OFF  2572544ul  // [B][C]                             4,096 f
#define TR_OFF  2576640ul  // [B][C]                             4,096 f
#define FW_OFF  2580736ul  // [B][19][C] gated final weights    77,824 f
// total 2,658,560 floats = 10.6 MB

__device__ __forceinline__ float sigm(float x) { return 1.0f / (1.0f + __expf(-x)); }

// ---------------- K0: zero the atomic-accumulated ws regions ----------------
__global__ void k0_zero(float* __restrict__ ws) {
  int i = blockIdx.x * 256 + threadIdx.x;
  if (i < 78080) ws[L_OFF + i] = 0.0f;  // covers l_sum (+pad) + ocr_un
}

// ---------------- K1: 3-conv (57 rows) + sigmoid chain + exp + denom ----------------
// One wg = 512 pixels of one batch; all 57 weight rows in LDS (114 KB).
__global__ __launch_bounds__(512)
void k1_scores(const float* __restrict__ x,
               const float* __restrict__ map_w, const float* __restrict__ map_b,
               const float* __restrict__ dist_w, const float* __restrict__ dist_b,
               const float* __restrict__ bnd_w, const float* __restrict__ bnd_b,
               float* __restrict__ ws) {
  constexpr int R = 3 * NN_;              // 57
  __shared__ float wlds[C_ * R];          // [c][r], broadcast reads
  const int tid = threadIdx.x;
  const int b = blockIdx.y;
  const int p = blockIdx.x * 512 + tid;

  for (int i = tid; i < R * C_; i += 512) {
    int r = i >> 9, c = i & (C_ - 1);
    float v;
    if (r < NN_)          v = map_w[r * C_ + c];
    else if (r < 2 * NN_) v = dist_w[(r - NN_) * C_ + c];
    else                  v = bnd_w[(r - 2 * NN_) * C_ + c];
    wlds[c * R + r] = v;
  }
  __syncthreads();

  float acc[R];
#pragma unroll
  for (int r = 0; r < R; ++r) acc[r] = 0.0f;

  const float* xp = x + ((size_t)b * C_) * HW_ + p;
  for (int c0 = 0; c0 < C_; c0 += 4) {
    float xv[4];
#pragma unroll
    for (int j = 0; j < 4; ++j) xv[j] = xp[(size_t)(c0 + j) * HW_];
#pragma unroll
    for (int j = 0; j < 4; ++j) {
      const float* wr = &wlds[(c0 + j) * R];
#pragma unroll
      for (int r = 0; r < R; ++r) acc[r] += wr[r] * xv[j];
    }
  }

  float* e_ws = ws + E_OFF;
  float* l_ws = ws + L_OFF;
#pragma unroll
  for (int n = 0; n < NN_; ++n) {
    float m  = acc[n]           + map_b[n];
    float dd = acc[NN_ + n]     + dist_b[n];
    float bb = acc[2 * NN_ + n] + bnd_b[n];
    dd = dd * sigm(m);
    bb = bb * sigm(dd);
    dd = dd + sigm(bb);
    float s = m + sigm(dd);
    float e = __expf(s);  // softmax numerator; |s|<~8 so no max-sub needed
    e_ws[((size_t)(b * NN_ + n) << 14) + p] = e;
    float t = e;
#pragma unroll
    for (int off = 32; off > 0; off >>= 1) t += __shfl_down(t, off, 64);
    if ((tid & 63) == 0) atomicAdd(&l_ws[b * NN_ + n], t);
  }
}

// ---------------- K2: ocr_un[b,n,c] = sum_p e[b,n,p] * x[b,c,p] ----------------
// x staged pixel-major->channel-major in LDS; e via wave-uniform (scalar) loads.
__global__ __launch_bounds__(256)
void k2_ocr(const float* __restrict__ x, float* __restrict__ ws) {
  __shared__ float xs[32][257];  // [pixel][channel], padded
  const int tid = threadIdx.x;
  const int pt = blockIdx.x, ct = blockIdx.y, b = blockIdx.z;
  const float* e_ws = ws + E_OFF;
  float acc[NN_];
#pragma unroll
  for (int n = 0; n < NN_; ++n) acc[n] = 0.f;
  const int cbase = ct * 256;
  const int p0 = pt * 1024;

  for (int pb = 0; pb < 1024; pb += 32) {
    const int pg = p0 + pb;
    // stage 256 channels x 32 pixels (2048 float4 loads, 8 per thread)
#pragma unroll
    for (int k = 0; k < 8; ++k) {
      int f = tid + k * 256;
      int cr = f >> 3, p4 = f & 7;  // 8 float4 (=32 px) per channel row
      const float4 v =
          *(const float4*)(x + (((size_t)(b * C_ + cbase + cr)) << 14) + pg + p4 * 4);
      xs[p4 * 4 + 0][cr] = v.x;
      xs[p4 * 4 + 1][cr] = v.y;
      xs[p4 * 4 + 2][cr] = v.z;
      xs[p4 * 4 + 3][cr] = v.w;
    }
    __syncthreads();
#pragma unroll 4
    for (int pp = 0; pp < 32; ++pp) {
      float xv = xs[pp][tid];
#pragma unroll
      for (int n = 0; n < NN_; ++n)
        acc[n] += e_ws[((size_t)(b * NN_ + n) << 14) + pg + pp] * xv;
    }
    __syncthreads();
  }
  float* ocr = ws + OCR_OFF;
#pragma unroll
  for (int n = 0; n < NN_; ++n)
    atomicAdd(&ocr[(b * NN_ + n) * C_ + cbase + tid], acc[n]);
}

// ---------------- K3a: normalize ocr, att softmax over N, ctx ----------------
__global__ __launch_bounds__(256)
void k3a_ctx(const float* __restrict__ mask_w, const float* __restrict__ mask_b,
             float* __restrict__ ws) {
  __shared__ float ocr_s[NN_ * C_];
  __shared__ float att_s[32];
  const int tid = threadIdx.x, b = blockIdx.x;
  const float* ocr_un = ws + OCR_OFF + (size_t)b * NN_ * C_;
  const float* l_ws = ws + L_OFF + b * NN_;
  for (int i = tid; i < NN_ * C_; i += 256) {
    int n = i >> 9;
    ocr_s[i] = ocr_un[i] / l_ws[n];
  }
  __syncthreads();
  const int wid = tid >> 6, lane = tid & 63;
  for (int n = wid; n < NN_; n += 4) {
    float v = 0.f;
    for (int c = lane; c < C_; c += 64) v += ocr_s[n * C_ + c] * mask_w[c];
#pragma unroll
    for (int off = 32; off > 0; off >>= 1) v += __shfl_down(v, off, 64);
    if (lane == 0) att_s[n] = v + mask_b[0];
  }
  __syncthreads();
  if (tid < 64) {
    float a = (lane < NN_) ? att_s[lane] : -1e30f;
    float mx = a;
#pragma unroll
    for (int off = 32; off > 0; off >>= 1) mx = fmaxf(mx, __shfl_xor(mx, off, 64));
    float e = (lane < NN_) ? __expf(a - mx) : 0.f;
    float s = e;
#pragma unroll
    for (int off = 32; off > 0; off >>= 1) s += __shfl_xor(s, off, 64);
    if (lane < NN_) att_s[lane] = e / s;
  }
  __syncthreads();
  float* ctx = ws + CTX_OFF + b * C_;
  for (int c = tid; c < C_; c += 256) {
    float v = 0.f;
#pragma unroll
    for (int n = 0; n < NN_; ++n) v += ocr_s[n * C_ + c] * att_s[n];
    ctx[c] = v;
  }
}

// ---------------- K3b: t1[b,m] = cm1_w[m,:] . ctx[b,:] + cm1_b ----------------
__global__ __launch_bounds__(256)
void k3b_t1(const float* __restrict__ cm1_w, const float* __restrict__ cm1_b,
            float* __restrict__ ws) {
  __shared__ float ctx_s[C_];
  const int tid = threadIdx.x, mt = blockIdx.x, b = blockIdx.y;
  const float* ctx = ws + CTX_OFF + b * C_;
  for (int i = tid; i < C_; i += 256) ctx_s[i] = ctx[i];
  __syncthreads();
  const int wid = tid >> 6, lane = tid & 63;
  float* t1 = ws + T1_OFF + b * C_;
  for (int mi = wid * 16; mi < wid * 16 + 16; ++mi) {
    int m = mt * 64 + mi;
    float v = 0.f;
    for (int c = lane; c < C_; c += 64) v += cm1_w[m * C_ + c] * ctx_s[c];
#pragma unroll
    for (int off = 32; off > 0; off >>= 1) v += __shfl_down(v, off, 64);
    if (lane == 0) t1[m] = v + cm1_b[m];
  }
}

// ---------------- K3c: LayerNorm + ReLU ----------------
__global__ __launch_bounds__(512)
void k3c_ln(const float* __restrict__ ln_g, const float* __restrict__ ln_b,
            float* __restrict__ ws) {
  __shared__ float red[16];
  const int tid = threadIdx.x, b = blockIdx.x;
  float t = ws[T1_OFF + b * C_ + tid];
  float s1 = t, s2 = t * t;
#pragma unroll
  for (int off = 32; off > 0; off >>= 1) {
    s1 += __shfl_down(s1, off, 64);
    s2 += __shfl_down(s2, off, 64);
  }
  const int wid = tid >> 6, lane = tid & 63;
  if (lane == 0) { red[wid] = s1; red[8 + wid] = s2; }
  __syncthreads();
  if (tid == 0) {
    float a = 0.f, bb = 0.f;
    for (int i = 0; i < 8; ++i) { a += red[i]; bb += red[8 + i]; }
    red[0] = a; red[8] = bb;
  }
  __syncthreads();
  float mean = red[0] * (1.0f / 512.0f);
  float var = red[8] * (1.0f / 512.0f) - mean * mean;  // biased var, per jnp.var
  float rs = rsqrtf(var + 1e-5f);
  float tr = (t - mean) * rs * ln_g[tid] + ln_b[tid];
  ws[TR_OFF + b * C_ + tid] = fmaxf(tr, 0.f);
}

// ---------------- K3d: t2 matvec + sigmoid gate + gated final weights ----------------
__global__ __launch_bounds__(256)
void k3d_gate(const float* __restrict__ cm2_w, const float* __restrict__ cm2_b,
              const float* __restrict__ fin_w, float* __restrict__ ws) {
  __shared__ float tr_s[C_];
  __shared__ float gl_s[64];
  const int tid = threadIdx.x, ct = blockIdx.x, b = blockIdx.y;
  for (int i = tid; i < C_; i += 256) tr_s[i] = ws[TR_OFF + b * C_ + i];
  __syncthreads();
  const int wid = tid >> 6, lane = tid & 63;
  for (int ci = wid * 16; ci < wid * 16 + 16; ++ci) {
    int cc = ct * 64 + ci;
    float v = 0.f;
    for (int m = lane; m < C_; m += 64) v += cm2_w[cc * C_ + m] * tr_s[m];
#pragma unroll
    for (int off = 32; off > 0; off >>= 1) v += __shfl_down(v, off, 64);
    if (lane == 0) gl_s[ci] = 1.0f + sigm(v + cm2_b[cc]);
  }
  __syncthreads();
  float* fw = ws + FW_OFF + (size_t)b * NN_ * C_;
  for (int i = tid; i < NN_ * 64; i += 256) {
    int n = i >> 6, ci = i & 63;
    int cc = ct * 64 + ci;
    fw[n * C_ + cc] = fin_w[n * C_ + cc] * gl_s[ci];
  }
}

// ---------------- K4: final conv with gated weights ----------------
__global__ __launch_bounds__(512)
void k4_out(const float* __restrict__ x, const float* __restrict__ fin_b,
            const float* __restrict__ ws, float* __restrict__ out) {
  __shared__ float wlds[C_ * 20];
  const int tid = threadIdx.x, b = blockIdx.y;
  const int p = blockIdx.x * 512 + tid;
  const float* fw = ws + FW_OFF + (size_t)b * NN_ * C_;
  for (int i = tid; i < NN_ * C_; i += 512) {
    int n = i >> 9, c = i & (C_ - 1);
    wlds[c * 20 + n] = fw[i];
  }
  __syncthreads();
  float acc[NN_];
#pragma unroll
  for (int n = 0; n < NN_; ++n) acc[n] = fin_b[n];
  const float* xp = x + ((size_t)b * C_) * HW_ + p;
  for (int c0 = 0; c0 < C_; c0 += 4) {
    float xv[4];
#pragma unroll
    for (int j = 0; j < 4; ++j) xv[j] = xp[(size_t)(c0 + j) * HW_];
#pragma unroll
    for (int j = 0; j < 4; ++j) {
      const float* wr = &wlds[(c0 + j) * 20];
#pragma unroll
      for (int n = 0; n < NN_; ++n) acc[n] += wr[n] * xv[j];
    }
  }
#pragma unroll
  for (int n = 0; n < NN_; ++n)
    out[((size_t)(b * NN_ + n) << 14) + p] = acc[n];
}

extern "C" void kernel_launch(void* const* d_in, const int* in_sizes, int n_in,
                              void* d_out, int out_size, void* d_ws, size_t ws_size,
                              hipStream_t stream) {
  const float* x      = (const float*)d_in[0];
  const float* map_w  = (const float*)d_in[1];
  const float* map_b  = (const float*)d_in[2];
  const float* dist_w = (const float*)d_in[3];
  const float* dist_b = (const float*)d_in[4];
  const float* bnd_w  = (const float*)d_in[5];
  const float* bnd_b  = (const float*)d_in[6];
  const float* mask_w = (const float*)d_in[7];
  const float* mask_b = (const float*)d_in[8];
  const float* cm1_w  = (const float*)d_in[9];
  const float* cm1_b  = (const float*)d_in[10];
  const float* ln_g   = (const float*)d_in[11];
  const float* ln_b   = (const float*)d_in[12];
  const float* cm2_w  = (const float*)d_in[13];
  const float* cm2_b  = (const float*)d_in[14];
  const float* fin_w  = (const float*)d_in[15];
  const float* fin_b  = (const float*)d_in[16];
  float* ws = (float*)d_ws;
  float* out = (float*)d_out;

  k0_zero<<<dim3(305), dim3(256), 0, stream>>>(ws);
  k1_scores<<<dim3(32, 8), dim3(512), 0, stream>>>(
      x, map_w, map_b, dist_w, dist_b, bnd_w, bnd_b, ws);
  k2_ocr<<<dim3(16, 2, 8), dim3(256), 0, stream>>>(x, ws);
  k3a_ctx<<<dim3(8), dim3(256), 0, stream>>>(mask_w, mask_b, ws);
  k3b_t1<<<dim3(8, 8), dim3(256), 0, stream>>>(cm1_w, cm1_b, ws);
  k3c_ln<<<dim3(8), dim3(512), 0, stream>>>(ln_g, ln_b, ws);
  k3d_gate<<<dim3(8, 8), dim3(256), 0, stream>>>(cm2_w, cm2_b, fin_w, ws);
  k4_out<<<dim3(32, 8), dim3(512), 0, stream>>>(x, fin_b, ws, out);
}

// Round 3
// 879.473 us; speedup vs baseline: 1.1195x; 1.1195x over previous
//
#include <hip/hip_runtime.h>

#define B_  8
#define C_  512
#define NN_ 19
#define HW_ 16384

typedef unsigned short u16;
typedef short s8v __attribute__((ext_vector_type(8)));
typedef float f4v __attribute__((ext_vector_type(4)));

// ---- workspace layout (float-word offsets) ----
#define E_OFF    0ul        // [8][19][16384] f32 exp(scores)      2,490,368 f
#define L_OFF    2490368ul  // [8][19] denominators (pad 256)            256 f
#define OCR_OFF  2490624ul  // [8][19][512] unnormalized ocr          77,824 f
#define CTX_OFF  2568448ul  // [8][512]                                4,096 f
#define T1_OFF   2572544ul  // [8][512]                                4,096 f
#define TR_OFF   2576640ul  // [8][512]                                4,096 f
#define FW_OFF   2580736ul  // [8][19][512] f32 gated W (fallback)   77,824 f
#define WP57_OFF 2658560ul  // [64][512] bf16 packed conv1 weights   16,384 f
#define WP4_OFF  2674944ul  // [8][32][512] bf16 gated final W       65,536 f
#define XT_OFF   2740480ul  // [8][16384][512] bf16 x^T          33,554,432 f
// fast-path total bytes = (2740480 + 33554432) * 4 = 145,179,648
#define FAST_WS_BYTES 145179648ull
#define WP57_U (WP57_OFF * 2)  // ushort index into ws
#define WP4_U  (WP4_OFF * 2)
#define XT_U   (XT_OFF * 2)

__device__ __forceinline__ float sigm(float x) { return 1.0f / (1.0f + __expf(-x)); }
__device__ __forceinline__ u16 f2bf(float f) {  // round-to-nearest-even
  unsigned x = __float_as_uint(f);
  return (u16)((x + 0x7FFFu + ((x >> 16) & 1u)) >> 16);
}

// ---------------- K0: zero accumulated/padded ws regions ----------------
__global__ void k0_zero(float* __restrict__ ws, int nwords) {
  int i = blockIdx.x * 256 + threadIdx.x;
  if (i < nwords) ws[L_OFF + i] = 0.0f;
}

// ---------------- KP: pack 57 conv rows (+0-pad to 64) into bf16 ----------------
__global__ void kp_packw(const float* __restrict__ map_w, const float* __restrict__ dist_w,
                         const float* __restrict__ bnd_w, float* __restrict__ ws) {
  int i = blockIdx.x * 256 + threadIdx.x;  // 64*512
  if (i >= 64 * C_) return;
  int r = i >> 9, c = i & (C_ - 1);
  float v = 0.f;
  if (r < NN_)          v = map_w[r * C_ + c];
  else if (r < 2 * NN_) v = dist_w[(r - NN_) * C_ + c];
  else if (r < 3 * NN_) v = bnd_w[(r - 2 * NN_) * C_ + c];
  ((u16*)ws)[WP57_U + i] = f2bf(v);
}

// ---------------- KT: x f32 [B][C][HW] -> xT bf16 [B][HW][C] ----------------
__global__ __launch_bounds__(256)
void kt_xT(const float* __restrict__ x, float* __restrict__ ws) {
  __shared__ u16 t[64 * 72];  // [px][c], stride 72
  const int tid = threadIdx.x;
  const int p0 = blockIdx.x * 64, c0 = blockIdx.y * 64, b = blockIdx.z;
  u16* xT = (u16*)ws + XT_U;
#pragma unroll
  for (int pass = 0; pass < 4; ++pass) {
    int cl = pass * 16 + (tid >> 4), p4 = tid & 15;
    float4 v = *(const float4*)(x + (((size_t)(b * C_ + c0 + cl)) << 14) + p0 + p4 * 4);
    t[(p4 * 4 + 0) * 72 + cl] = f2bf(v.x);
    t[(p4 * 4 + 1) * 72 + cl] = f2bf(v.y);
    t[(p4 * 4 + 2) * 72 + cl] = f2bf(v.z);
    t[(p4 * 4 + 3) * 72 + cl] = f2bf(v.w);
  }
  __syncthreads();
#pragma unroll
  for (int pass = 0; pass < 4; ++pass) {
    int px = pass * 16 + (tid >> 4), c4 = (tid & 15) * 4;
    ushort4 o;
    o.x = t[px * 72 + c4 + 0]; o.y = t[px * 72 + c4 + 1];
    o.z = t[px * 72 + c4 + 2]; o.w = t[px * 72 + c4 + 3];
    *(ushort4*)(xT + (((size_t)(b * HW_ + p0 + px)) << 9) + c0 + c4) = o;
  }
}

// ---------------- K1 (fast): MFMA 57-row conv + sigmoid chain + exp + denom ----------------
// WG = 256 thr (4 waves), 256 pixels; M=64(57), K=512 (8 chunks of 64), per-wave 64 px.
__global__ __launch_bounds__(256)
void k1_mfma(const float* __restrict__ ws_c,
             const float* __restrict__ map_b, const float* __restrict__ dist_b,
             const float* __restrict__ bnd_b, float* __restrict__ ws) {
  __shared__ __align__(16) char smem[66560];  // max(stage 46080, epi 64*260*4)
  u16* Xl = (u16*)smem;                       // [256 px][64 k] stride 72
  u16* Wl = Xl + 256 * 72;                    // [64 m][64 k] stride 72
  float* Sl = (float*)smem;                   // [64 m][256 px] stride 260

  const int tid = threadIdx.x;
  const int lane = tid & 63, w = tid >> 6;
  const int ln = lane & 15, quad = lane >> 4;
  const int lr = lane >> 3, lk = (lane & 7) * 8;
  const int b = blockIdx.y, p0 = blockIdx.x * 256;

  const u16* xT = (const u16*)ws_c + XT_U;
  const u16* wp = (const u16*)ws_c + WP57_U;
  const u16* xTb = xT + ((size_t)(b * HW_ + p0) << 9);

  f4v acc[4][4];
  const f4v fz = {0.f, 0.f, 0.f, 0.f};
#pragma unroll
  for (int mt = 0; mt < 4; ++mt)
#pragma unroll
    for (int nt = 0; nt < 4; ++nt) acc[mt][nt] = fz;

  for (int ck = 0; ck < 8; ++ck) {
    uint4 xv[8], wv[2];
#pragma unroll
    for (int t = 0; t < 8; ++t) {
      int px = w * 64 + t * 8 + lr;
      xv[t] = *(const uint4*)(xTb + (size_t)px * 512 + ck * 64 + lk);
    }
#pragma unroll
    for (int t = 0; t < 2; ++t) {
      int m = w * 16 + t * 8 + lr;
      wv[t] = *(const uint4*)(wp + (size_t)m * 512 + ck * 64 + lk);
    }
    __syncthreads();  // prior compute done before overwrite
#pragma unroll
    for (int t = 0; t < 8; ++t) *(uint4*)(&Xl[(w * 64 + t * 8 + lr) * 72 + lk]) = xv[t];
#pragma unroll
    for (int t = 0; t < 2; ++t) *(uint4*)(&Wl[(w * 16 + t * 8 + lr) * 72 + lk]) = wv[t];
    __syncthreads();
#pragma unroll
    for (int ks = 0; ks < 2; ++ks) {
      s8v af[4], bf[4];
#pragma unroll
      for (int mt = 0; mt < 4; ++mt)
        af[mt] = *(const s8v*)(&Wl[(mt * 16 + ln) * 72 + ks * 32 + quad * 8]);
#pragma unroll
      for (int nt = 0; nt < 4; ++nt)
        bf[nt] = *(const s8v*)(&Xl[(w * 64 + nt * 16 + ln) * 72 + ks * 32 + quad * 8]);
#pragma unroll
      for (int mt = 0; mt < 4; ++mt)
#pragma unroll
        for (int nt = 0; nt < 4; ++nt)
          acc[mt][nt] = __builtin_amdgcn_mfma_f32_16x16x32_bf16(af[mt], bf[nt], acc[mt][nt], 0, 0, 0);
    }
  }
  __syncthreads();
  // D layout: col(=px within tile)=lane&15, row(=m)=quad*4+reg  [m89 verified]
#pragma unroll
  for (int mt = 0; mt < 4; ++mt)
#pragma unroll
    for (int nt = 0; nt < 4; ++nt)
#pragma unroll
      for (int r = 0; r < 4; ++r)
        Sl[(mt * 16 + quad * 4 + r) * 260 + w * 64 + nt * 16 + ln] = acc[mt][nt][r];
  __syncthreads();

  float* e_ws = ws + E_OFF;
  float* l_ws = ws + L_OFF;
  const int px = tid;
#pragma unroll
  for (int n = 0; n < NN_; ++n) {
    float m  = Sl[n * 260 + px] + map_b[n];
    float dd = Sl[(NN_ + n) * 260 + px] + dist_b[n];
    float bb = Sl[(2 * NN_ + n) * 260 + px] + bnd_b[n];
    dd = dd * sigm(m);
    bb = bb * sigm(dd);
    dd = dd + sigm(bb);
    float s = m + sigm(dd);
    float e = __expf(s);
    e_ws[((size_t)(b * NN_ + n) << 14) + p0 + px] = e;
    float t = e;
#pragma unroll
    for (int off = 32; off > 0; off >>= 1) t += __shfl_down(t, off, 64);
    if (lane == 0) atomicAdd(&l_ws[b * NN_ + n], t);
  }
}

// ---------------- K2 (fast): ocr_un[b,n,c] += sum_p e[b,n,p]*xT[b,p,c] ----------------
__global__ __launch_bounds__(256)
void k2_fast(const float* __restrict__ ws_c, float* __restrict__ ws) {
  const int tid = threadIdx.x;
  const int b = blockIdx.y, p0 = blockIdx.x * 256;
  const u16* xT = (const u16*)ws_c + XT_U;
  const float* e_ws = ws_c + E_OFF;
  float a0[NN_], a1[NN_];
#pragma unroll
  for (int n = 0; n < NN_; ++n) { a0[n] = 0.f; a1[n] = 0.f; }
  for (int p = p0; p < p0 + 256; ++p) {
    unsigned xv = *(const unsigned*)(xT + (((size_t)(b * HW_ + p)) << 9) + tid * 2);
    float x0 = __uint_as_float(xv << 16);
    float x1 = __uint_as_float(xv & 0xFFFF0000u);
#pragma unroll
    for (int n = 0; n < NN_; ++n) {
      float ev = e_ws[((size_t)(b * NN_ + n) << 14) + p];  // wave-uniform -> s_load
      a0[n] += ev * x0;
      a1[n] += ev * x1;
    }
  }
  float* ocr = ws + OCR_OFF;
#pragma unroll
  for (int n = 0; n < NN_; ++n) {
    atomicAdd(&ocr[(b * NN_ + n) * C_ + tid * 2 + 0], a0[n]);
    atomicAdd(&ocr[(b * NN_ + n) * C_ + tid * 2 + 1], a1[n]);
  }
}

// ---------------- K3a: normalize ocr, att softmax over N, ctx ----------------
__global__ __launch_bounds__(256)
void k3a_ctx(const float* __restrict__ mask_w, const float* __restrict__ mask_b,
             float* __restrict__ ws) {
  __shared__ float ocr_s[NN_ * C_];
  __shared__ float att_s[32];
  const int tid = threadIdx.x, b = blockIdx.x;
  const float* ocr_un = ws + OCR_OFF + (size_t)b * NN_ * C_;
  const float* l_ws = ws + L_OFF + b * NN_;
  for (int i = tid; i < NN_ * C_; i += 256) {
    int n = i >> 9;
    ocr_s[i] = ocr_un[i] / l_ws[n];
  }
  __syncthreads();
  const int wid = tid >> 6, lane = tid & 63;
  for (int n = wid; n < NN_; n += 4) {
    float v = 0.f;
    for (int c = lane; c < C_; c += 64) v += ocr_s[n * C_ + c] * mask_w[c];
#pragma unroll
    for (int off = 32; off > 0; off >>= 1) v += __shfl_down(v, off, 64);
    if (lane == 0) att_s[n] = v + mask_b[0];
  }
  __syncthreads();
  if (tid < 64) {
    float a = (lane < NN_) ? att_s[lane] : -1e30f;
    float mx = a;
#pragma unroll
    for (int off = 32; off > 0; off >>= 1) mx = fmaxf(mx, __shfl_xor(mx, off, 64));
    float e = (lane < NN_) ? __expf(a - mx) : 0.f;
    float s = e;
#pragma unroll
    for (int off = 32; off > 0; off >>= 1) s += __shfl_xor(s, off, 64);
    if (lane < NN_) att_s[lane] = e / s;
  }
  __syncthreads();
  float* ctx = ws + CTX_OFF + b * C_;
  for (int c = tid; c < C_; c += 256) {
    float v = 0.f;
#pragma unroll
    for (int n = 0; n < NN_; ++n) v += ocr_s[n * C_ + c] * att_s[n];
    ctx[c] = v;
  }
}

// ---------------- K3b: t1 = cm1_w . ctx + cm1_b ----------------
__global__ __launch_bounds__(256)
void k3b_t1(const float* __restrict__ cm1_w, const float* __restrict__ cm1_b,
            float* __restrict__ ws) {
  __shared__ float ctx_s[C_];
  const int tid = threadIdx.x, mt = blockIdx.x, b = blockIdx.y;
  const float* ctx = ws + CTX_OFF + b * C_;
  for (int i = tid; i < C_; i += 256) ctx_s[i] = ctx[i];
  __syncthreads();
  const int wid = tid >> 6, lane = tid & 63;
  float* t1 = ws + T1_OFF + b * C_;
  for (int mi = wid * 16; mi < wid * 16 + 16; ++mi) {
    int m = mt * 64 + mi;
    float v = 0.f;
    for (int c = lane; c < C_; c += 64) v += cm1_w[m * C_ + c] * ctx_s[c];
#pragma unroll
    for (int off = 32; off > 0; off >>= 1) v += __shfl_down(v, off, 64);
    if (lane == 0) t1[m] = v + cm1_b[m];
  }
}

// ---------------- K3c: LayerNorm + ReLU ----------------
__global__ __launch_bounds__(512)
void k3c_ln(const float* __restrict__ ln_g, const float* __restrict__ ln_b,
            float* __restrict__ ws) {
  __shared__ float red[16];
  const int tid = threadIdx.x, b = blockIdx.x;
  float t = ws[T1_OFF + b * C_ + tid];
  float s1 = t, s2 = t * t;
#pragma unroll
  for (int off = 32; off > 0; off >>= 1) {
    s1 += __shfl_down(s1, off, 64);
    s2 += __shfl_down(s2, off, 64);
  }
  const int wid = tid >> 6, lane = tid & 63;
  if (lane == 0) { red[wid] = s1; red[8 + wid] = s2; }
  __syncthreads();
  if (tid == 0) {
    float a = 0.f, bb = 0.f;
    for (int i = 0; i < 8; ++i) { a += red[i]; bb += red[8 + i]; }
    red[0] = a; red[8] = bb;
  }
  __syncthreads();
  float mean = red[0] * (1.0f / 512.0f);
  float var = red[8] * (1.0f / 512.0f) - mean * mean;
  float rs = rsqrtf(var + 1e-5f);
  float tr = (t - mean) * rs * ln_g[tid] + ln_b[tid];
  ws[TR_OFF + b * C_ + tid] = fmaxf(tr, 0.f);
}

// ---------------- K3d: gate matvec + sigmoid; write gated final weights ----------------
__global__ __launch_bounds__(256)
void k3d_gate(const float* __restrict__ cm2_w, const float* __restrict__ cm2_b,
              const float* __restrict__ fin_w, float* __restrict__ ws, int fast) {
  __shared__ float tr_s[C_];
  __shared__ float gl_s[64];
  const int tid = threadIdx.x, ct = blockIdx.x, b = blockIdx.y;
  for (int i = tid; i < C_; i += 256) tr_s[i] = ws[TR_OFF + b * C_ + i];
  __syncthreads();
  const int wid = tid >> 6, lane = tid & 63;
  for (int ci = wid * 16; ci < wid * 16 + 16; ++ci) {
    int cc = ct * 64 + ci;
    float v = 0.f;
    for (int m = lane; m < C_; m += 64) v += cm2_w[cc * C_ + m] * tr_s[m];
#pragma unroll
    for (int off = 32; off > 0; off >>= 1) v += __shfl_down(v, off, 64);
    if (lane == 0) gl_s[ci] = 1.0f + sigm(v + cm2_b[cc]);
  }
  __syncthreads();
  if (fast) {
    u16* wp4 = (u16*)ws + WP4_U + (size_t)b * 32 * C_;
    for (int i = tid; i < NN_ * 64; i += 256) {
      int n = i >> 6, ci = i & 63;
      int cc = ct * 64 + ci;
      wp4[n * C_ + cc] = f2bf(fin_w[n * C_ + cc] * gl_s[ci]);
    }
  } else {
    float* fw = ws + FW_OFF + (size_t)b * NN_ * C_;
    for (int i = tid; i < NN_ * 64; i += 256) {
      int n = i >> 6, ci = i & 63;
      int cc = ct * 64 + ci;
      fw[n * C_ + cc] = fin_w[n * C_ + cc] * gl_s[ci];
    }
  }
}

// ---------------- K4 (fast): MFMA final conv ----------------
__global__ __launch_bounds__(256)
void k4_mfma(const float* __restrict__ ws_c, const float* __restrict__ fin_b,
             float* __restrict__ out) {
  __shared__ __align__(16) char smem[41472];  // max(stage 36864+4608, epi 32*260*4)
  u16* Xl = (u16*)smem;       // [256 px][64 k] stride 72
  u16* Wl = Xl + 256 * 72;    // [32 m][64 k] stride 72
  float* Sl = (float*)smem;   // [32 m][256 px] stride 260

  const int tid = threadIdx.x;
  const int lane = tid & 63, w = tid >> 6;
  const int ln = lane & 15, quad = lane >> 4;
  const int lr = lane >> 3, lk = (lane & 7) * 8;
  const int b = blockIdx.y, p0 = blockIdx.x * 256;

  const u16* xT = (const u16*)ws_c + XT_U;
  const u16* wp = (const u16*)ws_c + WP4_U + (size_t)b * 32 * C_;
  const u16* xTb = xT + ((size_t)(b * HW_ + p0) << 9);

  f4v acc[2][4];
  const f4v fz = {0.f, 0.f, 0.f, 0.f};
#pragma unroll
  for (int mt = 0; mt < 2; ++mt)
#pragma unroll
    for (int nt = 0; nt < 4; ++nt) acc[mt][nt] = fz;

  for (int ck = 0; ck < 8; ++ck) {
    uint4 xv[8], wv;
#pragma unroll
    for (int t = 0; t < 8; ++t) {
      int px = w * 64 + t * 8 + lr;
      xv[t] = *(const uint4*)(xTb + (size_t)px * 512 + ck * 64 + lk);
    }
    { int m = w * 8 + lr; wv = *(const uint4*)(wp + (size_t)m * 512 + ck * 64 + lk); }
    __syncthreads();
#pragma unroll
    for (int t = 0; t < 8; ++t) *(uint4*)(&Xl[(w * 64 + t * 8 + lr) * 72 + lk]) = xv[t];
    *(uint4*)(&Wl[(w * 8 + lr) * 72 + lk]) = wv;
    __syncthreads();
#pragma unroll
    for (int ks = 0; ks < 2; ++ks) {
      s8v af[2], bf[4];
#pragma unroll
      for (int mt = 0; mt < 2; ++mt)
        af[mt] = *(const s8v*)(&Wl[(mt * 16 + ln) * 72 + ks * 32 + quad * 8]);
#pragma unroll
      for (int nt = 0; nt < 4; ++nt)
        bf[nt] = *(const s8v*)(&Xl[(w * 64 + nt * 16 + ln) * 72 + ks * 32 + quad * 8]);
#pragma unroll
      for (int mt = 0; mt < 2; ++mt)
#pragma unroll
        for (int nt = 0; nt < 4; ++nt)
          acc[mt][nt] = __builtin_amdgcn_mfma_f32_16x16x32_bf16(af[mt], bf[nt], acc[mt][nt], 0, 0, 0);
    }
  }
  __syncthreads();
#pragma unroll
  for (int mt = 0; mt < 2; ++mt)
#pragma unroll
    for (int nt = 0; nt < 4; ++nt)
#pragma unroll
      for (int r = 0; r < 4; ++r)
        Sl[(mt * 16 + quad * 4 + r) * 260 + w * 64 + nt * 16 + ln] = acc[mt][nt][r];
  __syncthreads();
#pragma unroll
  for (int n = 0; n < NN_; ++n)
    out[((size_t)(b * NN_ + n) << 14) + p0 + tid] = Sl[n * 260 + tid] + fin_b[n];
}

// ================= fallback (proven R2) kernels =================
__global__ __launch_bounds__(512)
void k1_scores(const float* __restrict__ x,
               const float* __restrict__ map_w, const float* __restrict__ map_b,
               const float* __restrict__ dist_w, const float* __restrict__ dist_b,
               const float* __restrict__ bnd_w, const float* __restrict__ bnd_b,
               float* __restrict__ ws) {
  constexpr int R = 3 * NN_;
  __shared__ float wlds[C_ * R];
  const int tid = threadIdx.x;
  const int b = blockIdx.y;
  const int p = blockIdx.x * 512 + tid;
  for (int i = tid; i < R * C_; i += 512) {
    int r = i >> 9, c = i & (C_ - 1);
    float v;
    if (r < NN_)          v = map_w[r * C_ + c];
    else if (r < 2 * NN_) v = dist_w[(r - NN_) * C_ + c];
    else                  v = bnd_w[(r - 2 * NN_) * C_ + c];
    wlds[c * R + r] = v;
  }
  __syncthreads();
  float acc[R];
#pragma unroll
  for (int r = 0; r < R; ++r) acc[r] = 0.0f;
  const float* xp = x + ((size_t)b * C_) * HW_ + p;
  for (int c0 = 0; c0 < C_; c0 += 4) {
    float xv[4];
#pragma unroll
    for (int j = 0; j < 4; ++j) xv[j] = xp[(size_t)(c0 + j) * HW_];
#pragma unroll
    for (int j = 0; j < 4; ++j) {
      const float* wr = &wlds[(c0 + j) * R];
#pragma unroll
      for (int r = 0; r < R; ++r) acc[r] += wr[r] * xv[j];
    }
  }
  float* e_ws = ws + E_OFF;
  float* l_ws = ws + L_OFF;
#pragma unroll
  for (int n = 0; n < NN_; ++n) {
    float m  = acc[n]           + map_b[n];
    float dd = acc[NN_ + n]     + dist_b[n];
    float bb = acc[2 * NN_ + n] + bnd_b[n];
    dd = dd * sigm(m);
    bb = bb * sigm(dd);
    dd = dd + sigm(bb);
    float s = m + sigm(dd);
    float e = __expf(s);
    e_ws[((size_t)(b * NN_ + n) << 14) + p] = e;
    float t = e;
#pragma unroll
    for (int off = 32; off > 0; off >>= 1) t += __shfl_down(t, off, 64);
    if ((tid & 63) == 0) atomicAdd(&l_ws[b * NN_ + n], t);
  }
}

__global__ __launch_bounds__(256)
void k2_ocr(const float* __restrict__ x, float* __restrict__ ws) {
  __shared__ float xs[32][257];
  const int tid = threadIdx.x;
  const int pt = blockIdx.x, ct = blockIdx.y, b = blockIdx.z;
  const float* e_ws = ws + E_OFF;
  float acc[NN_];
#pragma unroll
  for (int n = 0; n < NN_; ++n) acc[n] = 0.f;
  const int cbase = ct * 256;
  const int p0 = pt * 1024;
  for (int pb = 0; pb < 1024; pb += 32) {
    const int pg = p0 + pb;
#pragma unroll
    for (int k = 0; k < 8; ++k) {
      int f = tid + k * 256;
      int cr = f >> 3, p4 = f & 7;
      const float4 v =
          *(const float4*)(x + (((size_t)(b * C_ + cbase + cr)) << 14) + pg + p4 * 4);
      xs[p4 * 4 + 0][cr] = v.x;
      xs[p4 * 4 + 1][cr] = v.y;
      xs[p4 * 4 + 2][cr] = v.z;
      xs[p4 * 4 + 3][cr] = v.w;
    }
    __syncthreads();
#pragma unroll 4
    for (int pp = 0; pp < 32; ++pp) {
      float xv = xs[pp][tid];
#pragma unroll
      for (int n = 0; n < NN_; ++n)
        acc[n] += e_ws[((size_t)(b * NN_ + n) << 14) + pg + pp] * xv;
    }
    __syncthreads();
  }
  float* ocr = ws + OCR_OFF;
#pragma unroll
  for (int n = 0; n < NN_; ++n)
    atomicAdd(&ocr[(b * NN_ + n) * C_ + cbase + tid], acc[n]);
}

__global__ __launch_bounds__(512)
void k4_out(const float* __restrict__ x, const float* __restrict__ fin_b,
            const float* __restrict__ ws, float* __restrict__ out) {
  __shared__ float wlds[C_ * 20];
  const int tid = threadIdx.x, b = blockIdx.y;
  const int p = blockIdx.x * 512 + tid;
  const float* fw = ws + FW_OFF + (size_t)b * NN_ * C_;
  for (int i = tid; i < NN_ * C_; i += 512) {
    int n = i >> 9, c = i & (C_ - 1);
    wlds[c * 20 + n] = fw[i];
  }
  __syncthreads();
  float acc[NN_];
#pragma unroll
  for (int n = 0; n < NN_; ++n) acc[n] = fin_b[n];
  const float* xp = x + ((size_t)b * C_) * HW_ + p;
  for (int c0 = 0; c0 < C_; c0 += 4) {
    float xv[4];
#pragma unroll
    for (int j = 0; j < 4; ++j) xv[j] = xp[(size_t)(c0 + j) * HW_];
#pragma unroll
    for (int j = 0; j < 4; ++j) {
      const float* wr = &wlds[(c0 + j) * 20];
#pragma unroll
      for (int n = 0; n < NN_; ++n) acc[n] += wr[n] * xv[j];
    }
  }
#pragma unroll
  for (int n = 0; n < NN_; ++n)
    out[((size_t)(b * NN_ + n) << 14) + p] = acc[n];
}

extern "C" void kernel_launch(void* const* d_in, const int* in_sizes, int n_in,
                              void* d_out, int out_size, void* d_ws, size_t ws_size,
                              hipStream_t stream) {
  const float* x      = (const float*)d_in[0];
  const float* map_w  = (const float*)d_in[1];
  const float* map_b  = (const float*)d_in[2];
  const float* dist_w = (const float*)d_in[3];
  const float* dist_b = (const float*)d_in[4];
  const float* bnd_w  = (const float*)d_in[5];
  const float* bnd_b  = (const float*)d_in[6];
  const float* mask_w = (const float*)d_in[7];
  const float* mask_b = (const float*)d_in[8];
  const float* cm1_w  = (const float*)d_in[9];
  const float* cm1_b  = (const float*)d_in[10];
  const float* ln_g   = (const float*)d_in[11];
  const float* ln_b   = (const float*)d_in[12];
  const float* cm2_w  = (const float*)d_in[13];
  const float* cm2_b  = (const float*)d_in[14];
  const float* fin_w  = (const float*)d_in[15];
  const float* fin_b  = (const float*)d_in[16];
  float* ws = (float*)d_ws;
  float* out = (float*)d_out;

  const bool fast = (ws_size >= FAST_WS_BYTES);  // constant per session: graph-safe

  if (fast) {
    int zw = 250112;  // L..end of WP4 pad
    k0_zero<<<dim3((zw + 255) / 256), dim3(256), 0, stream>>>(ws, zw);
    kp_packw<<<dim3(128), dim3(256), 0, stream>>>(map_w, dist_w, bnd_w, ws);
    kt_xT<<<dim3(256, 8, 8), dim3(256), 0, stream>>>(x, ws);
    k1_mfma<<<dim3(64, 8), dim3(256), 0, stream>>>(ws, map_b, dist_b, bnd_b, ws);
    k2_fast<<<dim3(64, 8), dim3(256), 0, stream>>>(ws, ws);
    k3a_ctx<<<dim3(8), dim3(256), 0, stream>>>(mask_w, mask_b, ws);
    k3b_t1<<<dim3(8, 8), dim3(256), 0, stream>>>(cm1_w, cm1_b, ws);
    k3c_ln<<<dim3(8), dim3(512), 0, stream>>>(ln_g, ln_b, ws);
    k3d_gate<<<dim3(8, 8), dim3(256), 0, stream>>>(cm2_w, cm2_b, fin_w, ws, 1);
    k4_mfma<<<dim3(64, 8), dim3(256), 0, stream>>>(ws, fin_b, out);
  } else {
    int zw = 78080;
    k0_zero<<<dim3((zw + 255) / 256), dim3(256), 0, stream>>>(ws, zw);
    k1_scores<<<dim3(32, 8), dim3(512), 0, stream>>>(
        x, map_w, map_b, dist_w, dist_b, bnd_w, bnd_b, ws);
    k2_ocr<<<dim3(16, 2, 8), dim3(256), 0, stream>>>(x, ws);
    k3a_ctx<<<dim3(8), dim3(256), 0, stream>>>(mask_w, mask_b, ws);
    k3b_t1<<<dim3(8, 8), dim3(256), 0, stream>>>(cm1_w, cm1_b, ws);
    k3c_ln<<<dim3(8), dim3(512), 0, stream>>>(ln_g, ln_b, ws);
    k3d_gate<<<dim3(8, 8), dim3(256), 0, stream>>>(cm2_w, cm2_b, fin_w, ws, 0);
    k4_out<<<dim3(32, 8), dim3(512), 0, stream>>>(x, fin_b, ws, out);
  }
}

// Round 4
// 778.406 us; speedup vs baseline: 1.2649x; 1.1298x over previous
//
#include <hip/hip_runtime.h>

#define B_  8
#define C_  512
#define NN_ 19
#define HW_ 16384

typedef unsigned short u16;
typedef short s8v __attribute__((ext_vector_type(8)));
typedef float f4v __attribute__((ext_vector_type(4)));

// ---- workspace layout (float-word offsets) ----
#define E_OFF    0ul        // [8][19][16384] f32 exp(scores)      2,490,368 f
#define L_OFF    2490368ul  // [8][19] denominators (pad 256)            256 f
#define OCR_OFF  2490624ul  // fast: [8][512][19] ocr^T; fallback: [8][19][512]
#define CTX_OFF  2568448ul  // [8][512]                                4,096 f
#define T1_OFF   2572544ul  // [8][512]                                4,096 f
#define TR_OFF   2576640ul  // [8][512]                                4,096 f
#define FW_OFF   2580736ul  // [8][19][512] f32 gated W (fallback)   77,824 f
#define WP57_OFF 2658560ul  // [64][512] bf16 packed conv1 weights   16,384 f
#define WP4_OFF  2674944ul  // [8][32][512] bf16 gated final W       65,536 f
#define XT_OFF   2740480ul  // [8][16384][512] bf16 x^T          33,554,432 f
#define FAST_WS_BYTES 145179648ull
#define WP57_U (WP57_OFF * 2)
#define WP4_U  (WP4_OFF * 2)
#define XT_U   (XT_OFF * 2)

__device__ __forceinline__ float sigm(float x) { return 1.0f / (1.0f + __expf(-x)); }
__device__ __forceinline__ u16 f2bf(float f) {  // round-to-nearest-even
  unsigned x = __float_as_uint(f);
  return (u16)((x + 0x7FFFu + ((x >> 16) & 1u)) >> 16);
}
__device__ __forceinline__ float bf2f(u16 u) {
  return __uint_as_float(((unsigned)u) << 16);
}
__device__ __forceinline__ s8v cvt8(float4 a, float4 b) {
  s8v r;
  r[0] = (short)f2bf(a.x); r[1] = (short)f2bf(a.y);
  r[2] = (short)f2bf(a.z); r[3] = (short)f2bf(a.w);
  r[4] = (short)f2bf(b.x); r[5] = (short)f2bf(b.y);
  r[6] = (short)f2bf(b.z); r[7] = (short)f2bf(b.w);
  return r;
}

// ---------------- K0: zero accumulated ws regions ----------------
__global__ void k0_zero(float* __restrict__ ws, int nwords) {
  int i = blockIdx.x * 256 + threadIdx.x;
  if (i < nwords) ws[L_OFF + i] = 0.0f;
}

// ---------------- KP: pack 57 conv rows (+0-pad to 64) into bf16 ----------------
__global__ void kp_packw(const float* __restrict__ map_w, const float* __restrict__ dist_w,
                         const float* __restrict__ bnd_w, float* __restrict__ ws) {
  int i = blockIdx.x * 256 + threadIdx.x;
  if (i >= 64 * C_) return;
  int r = i >> 9, c = i & (C_ - 1);
  float v = 0.f;
  if (r < NN_)          v = map_w[r * C_ + c];
  else if (r < 2 * NN_) v = dist_w[(r - NN_) * C_ + c];
  else if (r < 3 * NN_) v = bnd_w[(r - 2 * NN_) * C_ + c];
  ((u16*)ws)[WP57_U + i] = f2bf(v);
}

// ---------------- KT: x f32 [B][C][HW] -> xT bf16 [B][HW][C] ----------------
__global__ __launch_bounds__(256)
void kt_xT(const float* __restrict__ x, float* __restrict__ ws) {
  __shared__ u16 t[64 * 72];
  const int tid = threadIdx.x;
  const int p0 = blockIdx.x * 64, c0 = blockIdx.y * 64, b = blockIdx.z;
  u16* xT = (u16*)ws + XT_U;
#pragma unroll
  for (int pass = 0; pass < 4; ++pass) {
    int cl = pass * 16 + (tid >> 4), p4 = tid & 15;
    float4 v = *(const float4*)(x + (((size_t)(b * C_ + c0 + cl)) << 14) + p0 + p4 * 4);
    t[(p4 * 4 + 0) * 72 + cl] = f2bf(v.x);
    t[(p4 * 4 + 1) * 72 + cl] = f2bf(v.y);
    t[(p4 * 4 + 2) * 72 + cl] = f2bf(v.z);
    t[(p4 * 4 + 3) * 72 + cl] = f2bf(v.w);
  }
  __syncthreads();
#pragma unroll
  for (int pass = 0; pass < 4; ++pass) {
    int px = pass * 16 + (tid >> 4), c4 = (tid & 15) * 4;
    ushort4 o;
    o.x = t[px * 72 + c4 + 0]; o.y = t[px * 72 + c4 + 1];
    o.z = t[px * 72 + c4 + 2]; o.w = t[px * 72 + c4 + 3];
    *(ushort4*)(xT + (((size_t)(b * HW_ + p0 + px)) << 9) + c0 + c4) = o;
  }
}

// ---------------- K1 (fast): MFMA 57-row conv + sigmoid chain + exp + denom ----------------
__global__ __launch_bounds__(256)
void k1_mfma(const float* __restrict__ ws_c,
             const float* __restrict__ map_b, const float* __restrict__ dist_b,
             const float* __restrict__ bnd_b, float* __restrict__ ws) {
  __shared__ __align__(16) char smem[66560];
  u16* Xl = (u16*)smem;
  u16* Wl = Xl + 256 * 72;
  float* Sl = (float*)smem;

  const int tid = threadIdx.x;
  const int lane = tid & 63, w = tid >> 6;
  const int ln = lane & 15, quad = lane >> 4;
  const int lr = lane >> 3, lk = (lane & 7) * 8;
  const int b = blockIdx.y, p0 = blockIdx.x * 256;

  const u16* xT = (const u16*)ws_c + XT_U;
  const u16* wp = (const u16*)ws_c + WP57_U;
  const u16* xTb = xT + ((size_t)(b * HW_ + p0) << 9);

  f4v acc[4][4];
  const f4v fz = {0.f, 0.f, 0.f, 0.f};
#pragma unroll
  for (int mt = 0; mt < 4; ++mt)
#pragma unroll
    for (int nt = 0; nt < 4; ++nt) acc[mt][nt] = fz;

  for (int ck = 0; ck < 8; ++ck) {
    uint4 xv[8], wv[2];
#pragma unroll
    for (int t = 0; t < 8; ++t) {
      int px = w * 64 + t * 8 + lr;
      xv[t] = *(const uint4*)(xTb + (size_t)px * 512 + ck * 64 + lk);
    }
#pragma unroll
    for (int t = 0; t < 2; ++t) {
      int m = w * 16 + t * 8 + lr;
      wv[t] = *(const uint4*)(wp + (size_t)m * 512 + ck * 64 + lk);
    }
    __syncthreads();
#pragma unroll
    for (int t = 0; t < 8; ++t) *(uint4*)(&Xl[(w * 64 + t * 8 + lr) * 72 + lk]) = xv[t];
#pragma unroll
    for (int t = 0; t < 2; ++t) *(uint4*)(&Wl[(w * 16 + t * 8 + lr) * 72 + lk]) = wv[t];
    __syncthreads();
#pragma unroll
    for (int ks = 0; ks < 2; ++ks) {
      s8v af[4], bf[4];
#pragma unroll
      for (int mt = 0; mt < 4; ++mt)
        af[mt] = *(const s8v*)(&Wl[(mt * 16 + ln) * 72 + ks * 32 + quad * 8]);
#pragma unroll
      for (int nt = 0; nt < 4; ++nt)
        bf[nt] = *(const s8v*)(&Xl[(w * 64 + nt * 16 + ln) * 72 + ks * 32 + quad * 8]);
#pragma unroll
      for (int mt = 0; mt < 4; ++mt)
#pragma unroll
        for (int nt = 0; nt < 4; ++nt)
          acc[mt][nt] = __builtin_amdgcn_mfma_f32_16x16x32_bf16(af[mt], bf[nt], acc[mt][nt], 0, 0, 0);
    }
  }
  __syncthreads();
#pragma unroll
  for (int mt = 0; mt < 4; ++mt)
#pragma unroll
    for (int nt = 0; nt < 4; ++nt)
#pragma unroll
      for (int r = 0; r < 4; ++r)
        Sl[(mt * 16 + quad * 4 + r) * 260 + w * 64 + nt * 16 + ln] = acc[mt][nt][r];
  __syncthreads();

  float* e_ws = ws + E_OFF;
  float* l_ws = ws + L_OFF;
  const int px = tid;
#pragma unroll
  for (int n = 0; n < NN_; ++n) {
    float m  = Sl[n * 260 + px] + map_b[n];
    float dd = Sl[(NN_ + n) * 260 + px] + dist_b[n];
    float bb = Sl[(2 * NN_ + n) * 260 + px] + bnd_b[n];
    dd = dd * sigm(m);
    bb = bb * sigm(dd);
    dd = dd + sigm(bb);
    float s = m + sigm(dd);
    float e = __expf(s);
    e_ws[((size_t)(b * NN_ + n) << 14) + p0 + px] = e;
    float t = e;
#pragma unroll
    for (int off = 32; off > 0; off >>= 1) t += __shfl_down(t, off, 64);
    if (lane == 0) atomicAdd(&l_ws[b * NN_ + n], t);
  }
}

// ---------------- K2 (fast): MFMA  ocr^T[b,c,n] += sum_p x[b,c,p]*e[b,n,p] ----------------
// A = x rows (c), B = e rows (n): both have contraction dim p contiguous -> no LDS.
// e split hi/lo bf16 for ~f32 accuracy. Grid (ct=2, pt=32, b=8); K=512 per block.
__global__ __launch_bounds__(256)
void k2_mfma(const float* __restrict__ x, const float* __restrict__ ws_c,
             float* __restrict__ ws) {
  const int tid = threadIdx.x;
  const int lane = tid & 63, w = tid >> 6;
  const int ln = lane & 15, quad = lane >> 4;
  const int ct = blockIdx.x, pt = blockIdx.y, b = blockIdx.z;
  const int p0 = pt * 512;
  const int cw = ct * 256 + w * 64;

  const float* e_b = ws_c + E_OFF + (((size_t)b * NN_) << 14);
  const float* x_b = x + ((size_t)(b * C_)) * HW_;

  f4v acc[4][2];
  const f4v fz = {0.f, 0.f, 0.f, 0.f};
#pragma unroll
  for (int mt = 0; mt < 4; ++mt)
#pragma unroll
    for (int nt = 0; nt < 2; ++nt) acc[mt][nt] = fz;

#pragma unroll 2
  for (int ks = 0; ks < 16; ++ks) {
    const int kp = p0 + ks * 32 + quad * 8;
    s8v bhi[2], blo[2];
#pragma unroll
    for (int nt = 0; nt < 2; ++nt) {
      int n = nt * 16 + ln;
      float4 e0 = {0.f, 0.f, 0.f, 0.f}, e1 = {0.f, 0.f, 0.f, 0.f};
      if (n < NN_) {
        e0 = *(const float4*)(e_b + (((size_t)n) << 14) + kp);
        e1 = *(const float4*)(e_b + (((size_t)n) << 14) + kp + 4);
      }
      s8v h = cvt8(e0, e1);
      bhi[nt] = h;
      float4 l0, l1;
      l0.x = e0.x - bf2f((u16)h[0]); l0.y = e0.y - bf2f((u16)h[1]);
      l0.z = e0.z - bf2f((u16)h[2]); l0.w = e0.w - bf2f((u16)h[3]);
      l1.x = e1.x - bf2f((u16)h[4]); l1.y = e1.y - bf2f((u16)h[5]);
      l1.z = e1.z - bf2f((u16)h[6]); l1.w = e1.w - bf2f((u16)h[7]);
      blo[nt] = cvt8(l0, l1);
    }
#pragma unroll
    for (int mt = 0; mt < 4; ++mt) {
      const int c = cw + mt * 16 + ln;
      float4 x0 = *(const float4*)(x_b + (((size_t)c) << 14) + kp);
      float4 x1 = *(const float4*)(x_b + (((size_t)c) << 14) + kp + 4);
      s8v af = cvt8(x0, x1);
#pragma unroll
      for (int nt = 0; nt < 2; ++nt) {
        acc[mt][nt] = __builtin_amdgcn_mfma_f32_16x16x32_bf16(af, bhi[nt], acc[mt][nt], 0, 0, 0);
        acc[mt][nt] = __builtin_amdgcn_mfma_f32_16x16x32_bf16(af, blo[nt], acc[mt][nt], 0, 0, 0);
      }
    }
  }
  // D: row(c_local)=quad*4+r, col(n)=ln  -> atomic into ocr^T [b][c][19]
  float* ocr = ws + OCR_OFF;
#pragma unroll
  for (int nt = 0; nt < 2; ++nt) {
    int n = nt * 16 + ln;
    if (n < NN_) {
#pragma unroll
      for (int mt = 0; mt < 4; ++mt)
#pragma unroll
        for (int r = 0; r < 4; ++r) {
          int c = cw + mt * 16 + quad * 4 + r;
          atomicAdd(&ocr[((size_t)(b * C_ + c)) * NN_ + n], acc[mt][nt][r]);
        }
    }
  }
}

// ---------------- K3a: normalize ocr, att softmax over N, ctx ----------------
// tocr=1: ocr stored transposed [b][c][19]; tocr=0: [b][19][512]
__global__ __launch_bounds__(256)
void k3a_ctx(const float* __restrict__ mask_w, const float* __restrict__ mask_b,
             float* __restrict__ ws, int tocr) {
  __shared__ float ocr_s[NN_ * C_];
  __shared__ float att_s[32];
  const int tid = threadIdx.x, b = blockIdx.x;
  const float* ocr_un = ws + OCR_OFF + (size_t)b * NN_ * C_;
  const float* l_ws = ws + L_OFF + b * NN_;
  if (tocr) {
    for (int i = tid; i < NN_ * C_; i += 256) {
      int c = i / NN_, n = i - c * NN_;
      ocr_s[n * C_ + c] = ocr_un[i] / l_ws[n];
    }
  } else {
    for (int i = tid; i < NN_ * C_; i += 256) {
      int n = i >> 9;
      ocr_s[i] = ocr_un[i] / l_ws[n];
    }
  }
  __syncthreads();
  const int wid = tid >> 6, lane = tid & 63;
  for (int n = wid; n < NN_; n += 4) {
    float v = 0.f;
    for (int c = lane; c < C_; c += 64) v += ocr_s[n * C_ + c] * mask_w[c];
#pragma unroll
    for (int off = 32; off > 0; off >>= 1) v += __shfl_down(v, off, 64);
    if (lane == 0) att_s[n] = v + mask_b[0];
  }
  __syncthreads();
  if (tid < 64) {
    float a = (lane < NN_) ? att_s[lane] : -1e30f;
    float mx = a;
#pragma unroll
    for (int off = 32; off > 0; off >>= 1) mx = fmaxf(mx, __shfl_xor(mx, off, 64));
    float e = (lane < NN_) ? __expf(a - mx) : 0.f;
    float s = e;
#pragma unroll
    for (int off = 32; off > 0; off >>= 1) s += __shfl_xor(s, off, 64);
    if (lane < NN_) att_s[lane] = e / s;
  }
  __syncthreads();
  float* ctx = ws + CTX_OFF + b * C_;
  for (int c = tid; c < C_; c += 256) {
    float v = 0.f;
#pragma unroll
    for (int n = 0; n < NN_; ++n) v += ocr_s[n * C_ + c] * att_s[n];
    ctx[c] = v;
  }
}

// ---------------- K3b: t1 = cm1_w . ctx + cm1_b ----------------
__global__ __launch_bounds__(256)
void k3b_t1(const float* __restrict__ cm1_w, const float* __restrict__ cm1_b,
            float* __restrict__ ws) {
  __shared__ float ctx_s[C_];
  const int tid = threadIdx.x, mt = blockIdx.x, b = blockIdx.y;
  const float* ctx = ws + CTX_OFF + b * C_;
  for (int i = tid; i < C_; i += 256) ctx_s[i] = ctx[i];
  __syncthreads();
  const int wid = tid >> 6, lane = tid & 63;
  float* t1 = ws + T1_OFF + b * C_;
  for (int mi = wid * 16; mi < wid * 16 + 16; ++mi) {
    int m = mt * 64 + mi;
    float v = 0.f;
    for (int c = lane; c < C_; c += 64) v += cm1_w[m * C_ + c] * ctx_s[c];
#pragma unroll
    for (int off = 32; off > 0; off >>= 1) v += __shfl_down(v, off, 64);
    if (lane == 0) t1[m] = v + cm1_b[m];
  }
}

// ---------------- K3c: LayerNorm + ReLU ----------------
__global__ __launch_bounds__(512)
void k3c_ln(const float* __restrict__ ln_g, const float* __restrict__ ln_b,
            float* __restrict__ ws) {
  __shared__ float red[16];
  const int tid = threadIdx.x, b = blockIdx.x;
  float t = ws[T1_OFF + b * C_ + tid];
  float s1 = t, s2 = t * t;
#pragma unroll
  for (int off = 32; off > 0; off >>= 1) {
    s1 += __shfl_down(s1, off, 64);
    s2 += __shfl_down(s2, off, 64);
  }
  const int wid = tid >> 6, lane = tid & 63;
  if (lane == 0) { red[wid] = s1; red[8 + wid] = s2; }
  __syncthreads();
  if (tid == 0) {
    float a = 0.f, bb = 0.f;
    for (int i = 0; i < 8; ++i) { a += red[i]; bb += red[8 + i]; }
    red[0] = a; red[8] = bb;
  }
  __syncthreads();
  float mean = red[0] * (1.0f / 512.0f);
  float var = red[8] * (1.0f / 512.0f) - mean * mean;
  float rs = rsqrtf(var + 1e-5f);
  float tr = (t - mean) * rs * ln_g[tid] + ln_b[tid];
  ws[TR_OFF + b * C_ + tid] = fmaxf(tr, 0.f);
}

// ---------------- K3d: gate matvec + sigmoid; write gated final weights ----------------
__global__ __launch_bounds__(256)
void k3d_gate(const float* __restrict__ cm2_w, const float* __restrict__ cm2_b,
              const float* __restrict__ fin_w, float* __restrict__ ws, int fast) {
  __shared__ float tr_s[C_];
  __shared__ float gl_s[64];
  const int tid = threadIdx.x, ct = blockIdx.x, b = blockIdx.y;
  for (int i = tid; i < C_; i += 256) tr_s[i] = ws[TR_OFF + b * C_ + i];
  __syncthreads();
  const int wid = tid >> 6, lane = tid & 63;
  for (int ci = wid * 16; ci < wid * 16 + 16; ++ci) {
    int cc = ct * 64 + ci;
    float v = 0.f;
    for (int m = lane; m < C_; m += 64) v += cm2_w[cc * C_ + m] * tr_s[m];
#pragma unroll
    for (int off = 32; off > 0; off >>= 1) v += __shfl_down(v, off, 64);
    if (lane == 0) gl_s[ci] = 1.0f + sigm(v + cm2_b[cc]);
  }
  __syncthreads();
  if (fast) {
    u16* wp4 = (u16*)ws + WP4_U + (size_t)b * 32 * C_;
    for (int i = tid; i < NN_ * 64; i += 256) {
      int n = i >> 6, ci = i & 63;
      int cc = ct * 64 + ci;
      wp4[n * C_ + cc] = f2bf(fin_w[n * C_ + cc] * gl_s[ci]);
    }
  } else {
    float* fw = ws + FW_OFF + (size_t)b * NN_ * C_;
    for (int i = tid; i < NN_ * 64; i += 256) {
      int n = i >> 6, ci = i & 63;
      int cc = ct * 64 + ci;
      fw[n * C_ + cc] = fin_w[n * C_ + cc] * gl_s[ci];
    }
  }
}

// ---------------- K4 (fast): MFMA final conv ----------------
__global__ __launch_bounds__(256)
void k4_mfma(const float* __restrict__ ws_c, const float* __restrict__ fin_b,
             float* __restrict__ out) {
  __shared__ __align__(16) char smem[41472];
  u16* Xl = (u16*)smem;
  u16* Wl = Xl + 256 * 72;
  float* Sl = (float*)smem;

  const int tid = threadIdx.x;
  const int lane = tid & 63, w = tid >> 6;
  const int ln = lane & 15, quad = lane >> 4;
  const int lr = lane >> 3, lk = (lane & 7) * 8;
  const int b = blockIdx.y, p0 = blockIdx.x * 256;

  const u16* xT = (const u16*)ws_c + XT_U;
  const u16* wp = (const u16*)ws_c + WP4_U + (size_t)b * 32 * C_;
  const u16* xTb = xT + ((size_t)(b * HW_ + p0) << 9);

  f4v acc[2][4];
  const f4v fz = {0.f, 0.f, 0.f, 0.f};
#pragma unroll
  for (int mt = 0; mt < 2; ++mt)
#pragma unroll
    for (int nt = 0; nt < 4; ++nt) acc[mt][nt] = fz;

  for (int ck = 0; ck < 8; ++ck) {
    uint4 xv[8], wv;
#pragma unroll
    for (int t = 0; t < 8; ++t) {
      int px = w * 64 + t * 8 + lr;
      xv[t] = *(const uint4*)(xTb + (size_t)px * 512 + ck * 64 + lk);
    }
    { int m = w * 8 + lr; wv = *(const uint4*)(wp + (size_t)m * 512 + ck * 64 + lk); }
    __syncthreads();
#pragma unroll
    for (int t = 0; t < 8; ++t) *(uint4*)(&Xl[(w * 64 + t * 8 + lr) * 72 + lk]) = xv[t];
    *(uint4*)(&Wl[(w * 8 + lr) * 72 + lk]) = wv;
    __syncthreads();
#pragma unroll
    for (int ks = 0; ks < 2; ++ks) {
      s8v af[2], bf[4];
#pragma unroll
      for (int mt = 0; mt < 2; ++mt)
        af[mt] = *(const s8v*)(&Wl[(mt * 16 + ln) * 72 + ks * 32 + quad * 8]);
#pragma unroll
      for (int nt = 0; nt < 4; ++nt)
        bf[nt] = *(const s8v*)(&Xl[(w * 64 + nt * 16 + ln) * 72 + ks * 32 + quad * 8]);
#pragma unroll
      for (int mt = 0; mt < 2; ++mt)
#pragma unroll
        for (int nt = 0; nt < 4; ++nt)
          acc[mt][nt] = __builtin_amdgcn_mfma_f32_16x16x32_bf16(af[mt], bf[nt], acc[mt][nt], 0, 0, 0);
    }
  }
  __syncthreads();
#pragma unroll
  for (int mt = 0; mt < 2; ++mt)
#pragma unroll
    for (int nt = 0; nt < 4; ++nt)
#pragma unroll
      for (int r = 0; r < 4; ++r)
        Sl[(mt * 16 + quad * 4 + r) * 260 + w * 64 + nt * 16 + ln] = acc[mt][nt][r];
  __syncthreads();
#pragma unroll
  for (int n = 0; n < NN_; ++n)
    out[((size_t)(b * NN_ + n) << 14) + p0 + tid] = Sl[n * 260 + tid] + fin_b[n];
}

// ================= fallback (proven R2) kernels =================
__global__ __launch_bounds__(512)
void k1_scores(const float* __restrict__ x,
               const float* __restrict__ map_w, const float* __restrict__ map_b,
               const float* __restrict__ dist_w, const float* __restrict__ dist_b,
               const float* __restrict__ bnd_w, const float* __restrict__ bnd_b,
               float* __restrict__ ws) {
  constexpr int R = 3 * NN_;
  __shared__ float wlds[C_ * R];
  const int tid = threadIdx.x;
  const int b = blockIdx.y;
  const int p = blockIdx.x * 512 + tid;
  for (int i = tid; i < R * C_; i += 512) {
    int r = i >> 9, c = i & (C_ - 1);
    float v;
    if (r < NN_)          v = map_w[r * C_ + c];
    else if (r < 2 * NN_) v = dist_w[(r - NN_) * C_ + c];
    else                  v = bnd_w[(r - 2 * NN_) * C_ + c];
    wlds[c * R + r] = v;
  }
  __syncthreads();
  float acc[R];
#pragma unroll
  for (int r = 0; r < R; ++r) acc[r] = 0.0f;
  const float* xp = x + ((size_t)b * C_) * HW_ + p;
  for (int c0 = 0; c0 < C_; c0 += 4) {
    float xv[4];
#pragma unroll
    for (int j = 0; j < 4; ++j) xv[j] = xp[(size_t)(c0 + j) * HW_];
#pragma unroll
    for (int j = 0; j < 4; ++j) {
      const float* wr = &wlds[(c0 + j) * R];
#pragma unroll
      for (int r = 0; r < R; ++r) acc[r] += wr[r] * xv[j];
    }
  }
  float* e_ws = ws + E_OFF;
  float* l_ws = ws + L_OFF;
#pragma unroll
  for (int n = 0; n < NN_; ++n) {
    float m  = acc[n]           + map_b[n];
    float dd = acc[NN_ + n]     + dist_b[n];
    float bb = acc[2 * NN_ + n] + bnd_b[n];
    dd = dd * sigm(m);
    bb = bb * sigm(dd);
    dd = dd + sigm(bb);
    float s = m + sigm(dd);
    float e = __expf(s);
    e_ws[((size_t)(b * NN_ + n) << 14) + p] = e;
    float t = e;
#pragma unroll
    for (int off = 32; off > 0; off >>= 1) t += __shfl_down(t, off, 64);
    if ((tid & 63) == 0) atomicAdd(&l_ws[b * NN_ + n], t);
  }
}

__global__ __launch_bounds__(256)
void k2_ocr(const float* __restrict__ x, float* __restrict__ ws) {
  __shared__ float xs[32][257];
  const int tid = threadIdx.x;
  const int pt = blockIdx.x, ct = blockIdx.y, b = blockIdx.z;
  const float* e_ws = ws + E_OFF;
  float acc[NN_];
#pragma unroll
  for (int n = 0; n < NN_; ++n) acc[n] = 0.f;
  const int cbase = ct * 256;
  const int p0 = pt * 1024;
  for (int pb = 0; pb < 1024; pb += 32) {
    const int pg = p0 + pb;
#pragma unroll
    for (int k = 0; k < 8; ++k) {
      int f = tid + k * 256;
      int cr = f >> 3, p4 = f & 7;
      const float4 v =
          *(const float4*)(x + (((size_t)(b * C_ + cbase + cr)) << 14) + pg + p4 * 4);
      xs[p4 * 4 + 0][cr] = v.x;
      xs[p4 * 4 + 1][cr] = v.y;
      xs[p4 * 4 + 2][cr] = v.z;
      xs[p4 * 4 + 3][cr] = v.w;
    }
    __syncthreads();
#pragma unroll 4
    for (int pp = 0; pp < 32; ++pp) {
      float xv = xs[pp][tid];
#pragma unroll
      for (int n = 0; n < NN_; ++n)
        acc[n] += e_ws[((size_t)(b * NN_ + n) << 14) + pg + pp] * xv;
    }
    __syncthreads();
  }
  float* ocr = ws + OCR_OFF;
#pragma unroll
  for (int n = 0; n < NN_; ++n)
    atomicAdd(&ocr[(b * NN_ + n) * C_ + cbase + tid], acc[n]);
}

__global__ __launch_bounds__(512)
void k4_out(const float* __restrict__ x, const float* __restrict__ fin_b,
            const float* __restrict__ ws, float* __restrict__ out) {
  __shared__ float wlds[C_ * 20];
  const int tid = threadIdx.x, b = blockIdx.y;
  const int p = blockIdx.x * 512 + tid;
  const float* fw = ws + FW_OFF + (size_t)b * NN_ * C_;
  for (int i = tid; i < NN_ * C_; i += 512) {
    int n = i >> 9, c = i & (C_ - 1);
    wlds[c * 20 + n] = fw[i];
  }
  __syncthreads();
  float acc[NN_];
#pragma unroll
  for (int n = 0; n < NN_; ++n) acc[n] = fin_b[n];
  const float* xp = x + ((size_t)b * C_) * HW_ + p;
  for (int c0 = 0; c0 < C_; c0 += 4) {
    float xv[4];
#pragma unroll
    for (int j = 0; j < 4; ++j) xv[j] = xp[(size_t)(c0 + j) * HW_];
#pragma unroll
    for (int j = 0; j < 4; ++j) {
      const float* wr = &wlds[(c0 + j) * 20];
#pragma unroll
      for (int n = 0; n < NN_; ++n) acc[n] += wr[n] * xv[j];
    }
  }
#pragma unroll
  for (int n = 0; n < NN_; ++n)
    out[((size_t)(b * NN_ + n) << 14) + p] = acc[n];
}

extern "C" void kernel_launch(void* const* d_in, const int* in_sizes, int n_in,
                              void* d_out, int out_size, void* d_ws, size_t ws_size,
                              hipStream_t stream) {
  const float* x      = (const float*)d_in[0];
  const float* map_w  = (const float*)d_in[1];
  const float* map_b  = (const float*)d_in[2];
  const float* dist_w = (const float*)d_in[3];
  const float* dist_b = (const float*)d_in[4];
  const float* bnd_w  = (const float*)d_in[5];
  const float* bnd_b  = (const float*)d_in[6];
  const float* mask_w = (const float*)d_in[7];
  const float* mask_b = (const float*)d_in[8];
  const float* cm1_w  = (const float*)d_in[9];
  const float* cm1_b  = (const float*)d_in[10];
  const float* ln_g   = (const float*)d_in[11];
  const float* ln_b   = (const float*)d_in[12];
  const float* cm2_w  = (const float*)d_in[13];
  const float* cm2_b  = (const float*)d_in[14];
  const float* fin_w  = (const float*)d_in[15];
  const float* fin_b  = (const float*)d_in[16];
  float* ws = (float*)d_ws;
  float* out = (float*)d_out;

  const bool fast = (ws_size >= FAST_WS_BYTES);  // constant per session: graph-safe

  if (fast) {
    int zw = 250112;
    k0_zero<<<dim3((zw + 255) / 256), dim3(256), 0, stream>>>(ws, zw);
    kp_packw<<<dim3(128), dim3(256), 0, stream>>>(map_w, dist_w, bnd_w, ws);
    kt_xT<<<dim3(256, 8, 8), dim3(256), 0, stream>>>(x, ws);
    k1_mfma<<<dim3(64, 8), dim3(256), 0, stream>>>(ws, map_b, dist_b, bnd_b, ws);
    k2_mfma<<<dim3(2, 32, 8), dim3(256), 0, stream>>>(x, ws, ws);
    k3a_ctx<<<dim3(8), dim3(256), 0, stream>>>(mask_w, mask_b, ws, 1);
    k3b_t1<<<dim3(8, 8), dim3(256), 0, stream>>>(cm1_w, cm1_b, ws);
    k3c_ln<<<dim3(8), dim3(512), 0, stream>>>(ln_g, ln_b, ws);
    k3d_gate<<<dim3(8, 8), dim3(256), 0, stream>>>(cm2_w, cm2_b, fin_w, ws, 1);
    k4_mfma<<<dim3(64, 8), dim3(256), 0, stream>>>(ws, fin_b, out);
  } else {
    int zw = 78080;
    k0_zero<<<dim3((zw + 255) / 256), dim3(256), 0, stream>>>(ws, zw);
    k1_scores<<<dim3(32, 8), dim3(512), 0, stream>>>(
        x, map_w, map_b, dist_w, dist_b, bnd_w, bnd_b, ws);
    k2_ocr<<<dim3(16, 2, 8), dim3(256), 0, stream>>>(x, ws);
    k3a_ctx<<<dim3(8), dim3(256), 0, stream>>>(mask_w, mask_b, ws, 0);
    k3b_t1<<<dim3(8, 8), dim3(256), 0, stream>>>(cm1_w, cm1_b, ws);
    k3c_ln<<<dim3(8), dim3(512), 0, stream>>>(ln_g, ln_b, ws);
    k3d_gate<<<dim3(8, 8), dim3(256), 0, stream>>>(cm2_w, cm2_b, fin_w, ws, 0);
    k4_out<<<dim3(32, 8), dim3(512), 0, stream>>>(x, fin_b, ws, out);
  }
}

// Round 5
// 689.560 us; speedup vs baseline: 1.4279x; 1.1288x over previous
//
#include <hip/hip_runtime.h>

#define B_  8
#define C_  512
#define NN_ 19
#define HW_ 16384

typedef unsigned short u16;
typedef short s8v __attribute__((ext_vector_type(8)));
typedef float f4v __attribute__((ext_vector_type(4)));

// ---- workspace layout (float-word offsets) ----
#define E_OFF    0ul        // [8][19][16384] f32 exp(scores)      2,490,368 f
#define L_OFF    2490368ul  // [8][19] denominators (pad 256)            256 f
#define OCR_OFF  2490624ul  // fast: [8][512][19] ocr^T; fallback: [8][19][512]
#define CTX_OFF  2568448ul  // [8][512]                                4,096 f
#define T1_OFF   2572544ul  // [8][512]                                4,096 f
#define TR_OFF   2576640ul  // [8][512]                                4,096 f
#define FW_OFF   2580736ul  // [8][19][512] f32 gated W (fallback)   77,824 f
#define WP57_OFF 2658560ul  // [64][512] bf16 packed conv1 weights   16,384 f
#define WP4_OFF  2674944ul  // [8][32][512] bf16 gated final W       65,536 f
#define XT_OFF   2740480ul  // [8][16384][512] bf16 x^T          33,554,432 f
#define FAST_WS_BYTES 145179648ull
#define WP57_U (WP57_OFF * 2)
#define WP4_U  (WP4_OFF * 2)
#define XT_U   (XT_OFF * 2)

__device__ __forceinline__ float sigm(float x) { return 1.0f / (1.0f + __expf(-x)); }
__device__ __forceinline__ u16 f2bf(float f) {  // round-to-nearest-even
  unsigned x = __float_as_uint(f);
  return (u16)((x + 0x7FFFu + ((x >> 16) & 1u)) >> 16);
}
__device__ __forceinline__ float bf2f(u16 u) {
  return __uint_as_float(((unsigned)u) << 16);
}
__device__ __forceinline__ s8v cvt8(float4 a, float4 b) {
  s8v r;
  r[0] = (short)f2bf(a.x); r[1] = (short)f2bf(a.y);
  r[2] = (short)f2bf(a.z); r[3] = (short)f2bf(a.w);
  r[4] = (short)f2bf(b.x); r[5] = (short)f2bf(b.y);
  r[6] = (short)f2bf(b.z); r[7] = (short)f2bf(b.w);
  return r;
}

// ---------------- K0: zero accumulated ws regions ----------------
__global__ void k0_zero(float* __restrict__ ws, int nwords) {
  int i = blockIdx.x * 256 + threadIdx.x;
  if (i < nwords) ws[L_OFF + i] = 0.0f;
}

// ---------------- KP: pack 57 conv rows (+0-pad to 64) into bf16 ----------------
__global__ void kp_packw(const float* __restrict__ map_w, const float* __restrict__ dist_w,
                         const float* __restrict__ bnd_w, float* __restrict__ ws) {
  int i = blockIdx.x * 256 + threadIdx.x;
  if (i >= 64 * C_) return;
  int r = i >> 9, c = i & (C_ - 1);
  float v = 0.f;
  if (r < NN_)          v = map_w[r * C_ + c];
  else if (r < 2 * NN_) v = dist_w[(r - NN_) * C_ + c];
  else if (r < 3 * NN_) v = bnd_w[(r - 2 * NN_) * C_ + c];
  ((u16*)ws)[WP57_U + i] = f2bf(v);
}

// ---------------- KT: x f32 [B][C][HW] -> xT bf16 [B][HW][C] ----------------
__global__ __launch_bounds__(256)
void kt_xT(const float* __restrict__ x, float* __restrict__ ws) {
  __shared__ u16 t[64 * 72];
  const int tid = threadIdx.x;
  const int p0 = blockIdx.x * 64, c0 = blockIdx.y * 64, b = blockIdx.z;
  u16* xT = (u16*)ws + XT_U;
#pragma unroll
  for (int pass = 0; pass < 4; ++pass) {
    int cl = pass * 16 + (tid >> 4), p4 = tid & 15;
    float4 v = *(const float4*)(x + (((size_t)(b * C_ + c0 + cl)) << 14) + p0 + p4 * 4);
    t[(p4 * 4 + 0) * 72 + cl] = f2bf(v.x);
    t[(p4 * 4 + 1) * 72 + cl] = f2bf(v.y);
    t[(p4 * 4 + 2) * 72 + cl] = f2bf(v.z);
    t[(p4 * 4 + 3) * 72 + cl] = f2bf(v.w);
  }
  __syncthreads();
#pragma unroll
  for (int pass = 0; pass < 4; ++pass) {
    int px = pass * 16 + (tid >> 4), c4 = (tid & 15) * 4;
    ushort4 o;
    o.x = t[px * 72 + c4 + 0]; o.y = t[px * 72 + c4 + 1];
    o.z = t[px * 72 + c4 + 2]; o.w = t[px * 72 + c4 + 3];
    *(ushort4*)(xT + (((size_t)(b * HW_ + p0 + px)) << 9) + c0 + c4) = o;
  }
}

// ---------------- K1 (fast): MFMA 57-row conv + sigmoid chain + exp + denom ----------------
// Staging: load->immediate LDS write (short live range, no spill across barrier).
__global__ __launch_bounds__(256)
void k1_mfma(const float* __restrict__ ws_c,
             const float* __restrict__ map_b, const float* __restrict__ dist_b,
             const float* __restrict__ bnd_b, float* __restrict__ ws) {
  __shared__ __align__(16) char smem[66560];
  u16* Xl = (u16*)smem;
  u16* Wl = Xl + 256 * 72;
  float* Sl = (float*)smem;

  const int tid = threadIdx.x;
  const int lane = tid & 63, w = tid >> 6;
  const int ln = lane & 15, quad = lane >> 4;
  const int lr = lane >> 3, lk = (lane & 7) * 8;
  const int b = blockIdx.y, p0 = blockIdx.x * 256;

  const u16* xT = (const u16*)ws_c + XT_U;
  const u16* wp = (const u16*)ws_c + WP57_U;
  const u16* xTb = xT + ((size_t)(b * HW_ + p0) << 9);

  f4v acc[4][4];
  const f4v fz = {0.f, 0.f, 0.f, 0.f};
#pragma unroll
  for (int mt = 0; mt < 4; ++mt)
#pragma unroll
    for (int nt = 0; nt < 4; ++nt) acc[mt][nt] = fz;

  for (int ck = 0; ck < 8; ++ck) {
    __syncthreads();  // prior MFMA reads done before overwrite
#pragma unroll
    for (int t = 0; t < 8; ++t) {
      int px = w * 64 + t * 8 + lr;
      uint4 v = *(const uint4*)(xTb + (size_t)px * 512 + ck * 64 + lk);
      *(uint4*)(&Xl[px * 72 + lk]) = v;
    }
#pragma unroll
    for (int t = 0; t < 2; ++t) {
      int m = w * 16 + t * 8 + lr;
      uint4 v = *(const uint4*)(wp + (size_t)m * 512 + ck * 64 + lk);
      *(uint4*)(&Wl[m * 72 + lk]) = v;
    }
    __syncthreads();
#pragma unroll
    for (int ks = 0; ks < 2; ++ks) {
      s8v af[4], bf[4];
#pragma unroll
      for (int mt = 0; mt < 4; ++mt)
        af[mt] = *(const s8v*)(&Wl[(mt * 16 + ln) * 72 + ks * 32 + quad * 8]);
#pragma unroll
      for (int nt = 0; nt < 4; ++nt)
        bf[nt] = *(const s8v*)(&Xl[(w * 64 + nt * 16 + ln) * 72 + ks * 32 + quad * 8]);
#pragma unroll
      for (int mt = 0; mt < 4; ++mt)
#pragma unroll
        for (int nt = 0; nt < 4; ++nt)
          acc[mt][nt] = __builtin_amdgcn_mfma_f32_16x16x32_bf16(af[mt], bf[nt], acc[mt][nt], 0, 0, 0);
    }
  }
  __syncthreads();
#pragma unroll
  for (int mt = 0; mt < 4; ++mt)
#pragma unroll
    for (int nt = 0; nt < 4; ++nt)
#pragma unroll
      for (int r = 0; r < 4; ++r)
        Sl[(mt * 16 + quad * 4 + r) * 260 + w * 64 + nt * 16 + ln] = acc[mt][nt][r];
  __syncthreads();

  float* e_ws = ws + E_OFF;
  float* l_ws = ws + L_OFF;
  const int px = tid;
#pragma unroll
  for (int n = 0; n < NN_; ++n) {
    float m  = Sl[n * 260 + px] + map_b[n];
    float dd = Sl[(NN_ + n) * 260 + px] + dist_b[n];
    float bb = Sl[(2 * NN_ + n) * 260 + px] + bnd_b[n];
    dd = dd * sigm(m);
    bb = bb * sigm(dd);
    dd = dd + sigm(bb);
    float s = m + sigm(dd);
    float e = __expf(s);
    e_ws[((size_t)(b * NN_ + n) << 14) + p0 + px] = e;
    float t = e;
#pragma unroll
    for (int off = 32; off > 0; off >>= 1) t += __shfl_down(t, off, 64);
    if (lane == 0) atomicAdd(&l_ws[b * NN_ + n], t);
  }
}

// ---------------- K2 (fast): MFMA  ocr^T[b,c,n] += sum_p x[b,c,p]*e[b,n,p] ----------------
__global__ __launch_bounds__(256)
void k2_mfma(const float* __restrict__ x, const float* __restrict__ ws_c,
             float* __restrict__ ws) {
  const int tid = threadIdx.x;
  const int lane = tid & 63, w = tid >> 6;
  const int ln = lane & 15, quad = lane >> 4;
  const int ct = blockIdx.x, pt = blockIdx.y, b = blockIdx.z;
  const int p0 = pt * 512;
  const int cw = ct * 256 + w * 64;

  const float* e_b = ws_c + E_OFF + (((size_t)b * NN_) << 14);
  const float* x_b = x + ((size_t)(b * C_)) * HW_;

  f4v acc[4][2];
  const f4v fz = {0.f, 0.f, 0.f, 0.f};
#pragma unroll
  for (int mt = 0; mt < 4; ++mt)
#pragma unroll
    for (int nt = 0; nt < 2; ++nt) acc[mt][nt] = fz;

#pragma unroll 2
  for (int ks = 0; ks < 16; ++ks) {
    const int kp = p0 + ks * 32 + quad * 8;
    s8v bhi[2], blo[2];
#pragma unroll
    for (int nt = 0; nt < 2; ++nt) {
      int n = nt * 16 + ln;
      float4 e0 = {0.f, 0.f, 0.f, 0.f}, e1 = {0.f, 0.f, 0.f, 0.f};
      if (n < NN_) {
        e0 = *(const float4*)(e_b + (((size_t)n) << 14) + kp);
        e1 = *(const float4*)(e_b + (((size_t)n) << 14) + kp + 4);
      }
      s8v h = cvt8(e0, e1);
      bhi[nt] = h;
      float4 l0, l1;
      l0.x = e0.x - bf2f((u16)h[0]); l0.y = e0.y - bf2f((u16)h[1]);
      l0.z = e0.z - bf2f((u16)h[2]); l0.w = e0.w - bf2f((u16)h[3]);
      l1.x = e1.x - bf2f((u16)h[4]); l1.y = e1.y - bf2f((u16)h[5]);
      l1.z = e1.z - bf2f((u16)h[6]); l1.w = e1.w - bf2f((u16)h[7]);
      blo[nt] = cvt8(l0, l1);
    }
#pragma unroll
    for (int mt = 0; mt < 4; ++mt) {
      const int c = cw + mt * 16 + ln;
      float4 x0 = *(const float4*)(x_b + (((size_t)c) << 14) + kp);
      float4 x1 = *(const float4*)(x_b + (((size_t)c) << 14) + kp + 4);
      s8v af = cvt8(x0, x1);
#pragma unroll
      for (int nt = 0; nt < 2; ++nt) {
        acc[mt][nt] = __builtin_amdgcn_mfma_f32_16x16x32_bf16(af, bhi[nt], acc[mt][nt], 0, 0, 0);
        acc[mt][nt] = __builtin_amdgcn_mfma_f32_16x16x32_bf16(af, blo[nt], acc[mt][nt], 0, 0, 0);
      }
    }
  }
  float* ocr = ws + OCR_OFF;
#pragma unroll
  for (int nt = 0; nt < 2; ++nt) {
    int n = nt * 16 + ln;
    if (n < NN_) {
#pragma unroll
      for (int mt = 0; mt < 4; ++mt)
#pragma unroll
        for (int r = 0; r < 4; ++r) {
          int c = cw + mt * 16 + quad * 4 + r;
          atomicAdd(&ocr[((size_t)(b * C_ + c)) * NN_ + n], acc[mt][nt][r]);
        }
    }
  }
}

// ---------------- K3a: normalize ocr, att softmax over N, ctx ----------------
__global__ __launch_bounds__(256)
void k3a_ctx(const float* __restrict__ mask_w, const float* __restrict__ mask_b,
             float* __restrict__ ws, int tocr) {
  __shared__ float ocr_s[NN_ * C_];
  __shared__ float att_s[32];
  const int tid = threadIdx.x, b = blockIdx.x;
  const float* ocr_un = ws + OCR_OFF + (size_t)b * NN_ * C_;
  const float* l_ws = ws + L_OFF + b * NN_;
  if (tocr) {
    for (int i = tid; i < NN_ * C_; i += 256) {
      int c = i / NN_, n = i - c * NN_;
      ocr_s[n * C_ + c] = ocr_un[i] / l_ws[n];
    }
  } else {
    for (int i = tid; i < NN_ * C_; i += 256) {
      int n = i >> 9;
      ocr_s[i] = ocr_un[i] / l_ws[n];
    }
  }
  __syncthreads();
  const int wid = tid >> 6, lane = tid & 63;
  for (int n = wid; n < NN_; n += 4) {
    float v = 0.f;
    for (int c = lane; c < C_; c += 64) v += ocr_s[n * C_ + c] * mask_w[c];
#pragma unroll
    for (int off = 32; off > 0; off >>= 1) v += __shfl_down(v, off, 64);
    if (lane == 0) att_s[n] = v + mask_b[0];
  }
  __syncthreads();
  if (tid < 64) {
    float a = (lane < NN_) ? att_s[lane] : -1e30f;
    float mx = a;
#pragma unroll
    for (int off = 32; off > 0; off >>= 1) mx = fmaxf(mx, __shfl_xor(mx, off, 64));
    float e = (lane < NN_) ? __expf(a - mx) : 0.f;
    float s = e;
#pragma unroll
    for (int off = 32; off > 0; off >>= 1) s += __shfl_xor(s, off, 64);
    if (lane < NN_) att_s[lane] = e / s;
  }
  __syncthreads();
  float* ctx = ws + CTX_OFF + b * C_;
  for (int c = tid; c < C_; c += 256) {
    float v = 0.f;
#pragma unroll
    for (int n = 0; n < NN_; ++n) v += ocr_s[n * C_ + c] * att_s[n];
    ctx[c] = v;
  }
}

// ---------------- K3b: t1 = cm1_w . ctx + cm1_b ----------------
__global__ __launch_bounds__(256)
void k3b_t1(const float* __restrict__ cm1_w, const float* __restrict__ cm1_b,
            float* __restrict__ ws) {
  __shared__ float ctx_s[C_];
  const int tid = threadIdx.x, mt = blockIdx.x, b = blockIdx.y;
  const float* ctx = ws + CTX_OFF + b * C_;
  for (int i = tid; i < C_; i += 256) ctx_s[i] = ctx[i];
  __syncthreads();
  const int wid = tid >> 6, lane = tid & 63;
  float* t1 = ws + T1_OFF + b * C_;
  for (int mi = wid * 16; mi < wid * 16 + 16; ++mi) {
    int m = mt * 64 + mi;
    float v = 0.f;
    for (int c = lane; c < C_; c += 64) v += cm1_w[m * C_ + c] * ctx_s[c];
#pragma unroll
    for (int off = 32; off > 0; off >>= 1) v += __shfl_down(v, off, 64);
    if (lane == 0) t1[m] = v + cm1_b[m];
  }
}

// ---------------- K3c: LayerNorm + ReLU ----------------
__global__ __launch_bounds__(512)
void k3c_ln(const float* __restrict__ ln_g, const float* __restrict__ ln_b,
            float* __restrict__ ws) {
  __shared__ float red[16];
  const int tid = threadIdx.x, b = blockIdx.x;
  float t = ws[T1_OFF + b * C_ + tid];
  float s1 = t, s2 = t * t;
#pragma unroll
  for (int off = 32; off > 0; off >>= 1) {
    s1 += __shfl_down(s1, off, 64);
    s2 += __shfl_down(s2, off, 64);
  }
  const int wid = tid >> 6, lane = tid & 63;
  if (lane == 0) { red[wid] = s1; red[8 + wid] = s2; }
  __syncthreads();
  if (tid == 0) {
    float a = 0.f, bb = 0.f;
    for (int i = 0; i < 8; ++i) { a += red[i]; bb += red[8 + i]; }
    red[0] = a; red[8] = bb;
  }
  __syncthreads();
  float mean = red[0] * (1.0f / 512.0f);
  float var = red[8] * (1.0f / 512.0f) - mean * mean;
  float rs = rsqrtf(var + 1e-5f);
  float tr = (t - mean) * rs * ln_g[tid] + ln_b[tid];
  ws[TR_OFF + b * C_ + tid] = fmaxf(tr, 0.f);
}

// ---------------- K3d: gate matvec + sigmoid; write gated final weights ----------------
__global__ __launch_bounds__(256)
void k3d_gate(const float* __restrict__ cm2_w, const float* __restrict__ cm2_b,
              const float* __restrict__ fin_w, float* __restrict__ ws, int fast) {
  __shared__ float tr_s[C_];
  __shared__ float gl_s[64];
  const int tid = threadIdx.x, ct = blockIdx.x, b = blockIdx.y;
  for (int i = tid; i < C_; i += 256) tr_s[i] = ws[TR_OFF + b * C_ + i];
  __syncthreads();
  const int wid = tid >> 6, lane = tid & 63;
  for (int ci = wid * 16; ci < wid * 16 + 16; ++ci) {
    int cc = ct * 64 + ci;
    float v = 0.f;
    for (int m = lane; m < C_; m += 64) v += cm2_w[cc * C_ + m] * tr_s[m];
#pragma unroll
    for (int off = 32; off > 0; off >>= 1) v += __shfl_down(v, off, 64);
    if (lane == 0) gl_s[ci] = 1.0f + sigm(v + cm2_b[cc]);
  }
  __syncthreads();
  if (fast) {
    u16* wp4 = (u16*)ws + WP4_U + (size_t)b * 32 * C_;
    for (int i = tid; i < NN_ * 64; i += 256) {
      int n = i >> 6, ci = i & 63;
      int cc = ct * 64 + ci;
      wp4[n * C_ + cc] = f2bf(fin_w[n * C_ + cc] * gl_s[ci]);
    }
  } else {
    float* fw = ws + FW_OFF + (size_t)b * NN_ * C_;
    for (int i = tid; i < NN_ * 64; i += 256) {
      int n = i >> 6, ci = i & 63;
      int cc = ct * 64 + ci;
      fw[n * C_ + cc] = fin_w[n * C_ + cc] * gl_s[ci];
    }
  }
}

// ---------------- K4 (fast): MFMA final conv ----------------
__global__ __launch_bounds__(256)
void k4_mfma(const float* __restrict__ ws_c, const float* __restrict__ fin_b,
             float* __restrict__ out) {
  __shared__ __align__(16) char smem[41472];
  u16* Xl = (u16*)smem;
  u16* Wl = Xl + 256 * 72;
  float* Sl = (float*)smem;

  const int tid = threadIdx.x;
  const int lane = tid & 63, w = tid >> 6;
  const int ln = lane & 15, quad = lane >> 4;
  const int lr = lane >> 3, lk = (lane & 7) * 8;
  const int b = blockIdx.y, p0 = blockIdx.x * 256;

  const u16* xT = (const u16*)ws_c + XT_U;
  const u16* wp = (const u16*)ws_c + WP4_U + (size_t)b * 32 * C_;
  const u16* xTb = xT + ((size_t)(b * HW_ + p0) << 9);

  f4v acc[2][4];
  const f4v fz = {0.f, 0.f, 0.f, 0.f};
#pragma unroll
  for (int mt = 0; mt < 2; ++mt)
#pragma unroll
    for (int nt = 0; nt < 4; ++nt) acc[mt][nt] = fz;

  for (int ck = 0; ck < 8; ++ck) {
    __syncthreads();
#pragma unroll
    for (int t = 0; t < 8; ++t) {
      int px = w * 64 + t * 8 + lr;
      uint4 v = *(const uint4*)(xTb + (size_t)px * 512 + ck * 64 + lk);
      *(uint4*)(&Xl[px * 72 + lk]) = v;
    }
    {
      int m = w * 8 + lr;
      uint4 v = *(const uint4*)(wp + (size_t)m * 512 + ck * 64 + lk);
      *(uint4*)(&Wl[m * 72 + lk]) = v;
    }
    __syncthreads();
#pragma unroll
    for (int ks = 0; ks < 2; ++ks) {
      s8v af[2], bf[4];
#pragma unroll
      for (int mt = 0; mt < 2; ++mt)
        af[mt] = *(const s8v*)(&Wl[(mt * 16 + ln) * 72 + ks * 32 + quad * 8]);
#pragma unroll
      for (int nt = 0; nt < 4; ++nt)
        bf[nt] = *(const s8v*)(&Xl[(w * 64 + nt * 16 + ln) * 72 + ks * 32 + quad * 8]);
#pragma unroll
      for (int mt = 0; mt < 2; ++mt)
#pragma unroll
        for (int nt = 0; nt < 4; ++nt)
          acc[mt][nt] = __builtin_amdgcn_mfma_f32_16x16x32_bf16(af[mt], bf[nt], acc[mt][nt], 0, 0, 0);
    }
  }
  __syncthreads();
#pragma unroll
  for (int mt = 0; mt < 2; ++mt)
#pragma unroll
    for (int nt = 0; nt < 4; ++nt)
#pragma unroll
      for (int r = 0; r < 4; ++r)
        Sl[(mt * 16 + quad * 4 + r) * 260 + w * 64 + nt * 16 + ln] = acc[mt][nt][r];
  __syncthreads();
#pragma unroll
  for (int n = 0; n < NN_; ++n)
    out[((size_t)(b * NN_ + n) << 14) + p0 + tid] = Sl[n * 260 + tid] + fin_b[n];
}

// ================= fallback (proven R2) kernels =================
__global__ __launch_bounds__(512)
void k1_scores(const float* __restrict__ x,
               const float* __restrict__ map_w, const float* __restrict__ map_b,
               const float* __restrict__ dist_w, const float* __restrict__ dist_b,
               const float* __restrict__ bnd_w, const float* __restrict__ bnd_b,
               float* __restrict__ ws) {
  constexpr int R = 3 * NN_;
  __shared__ float wlds[C_ * R];
  const int tid = threadIdx.x;
  const int b = blockIdx.y;
  const int p = blockIdx.x * 512 + tid;
  for (int i = tid; i < R * C_; i += 512) {
    int r = i >> 9, c = i & (C_ - 1);
    float v;
    if (r < NN_)          v = map_w[r * C_ + c];
    else if (r < 2 * NN_) v = dist_w[(r - NN_) * C_ + c];
    else                  v = bnd_w[(r - 2 * NN_) * C_ + c];
    wlds[c * R + r] = v;
  }
  __syncthreads();
  float acc[R];
#pragma unroll
  for (int r = 0; r < R; ++r) acc[r] = 0.0f;
  const float* xp = x + ((size_t)b * C_) * HW_ + p;
  for (int c0 = 0; c0 < C_; c0 += 4) {
    float xv[4];
#pragma unroll
    for (int j = 0; j < 4; ++j) xv[j] = xp[(size_t)(c0 + j) * HW_];
#pragma unroll
    for (int j = 0; j < 4; ++j) {
      const float* wr = &wlds[(c0 + j) * R];
#pragma unroll
      for (int r = 0; r < R; ++r) acc[r] += wr[r] * xv[j];
    }
  }
  float* e_ws = ws + E_OFF;
  float* l_ws = ws + L_OFF;
#pragma unroll
  for (int n = 0; n < NN_; ++n) {
    float m  = acc[n]           + map_b[n];
    float dd = acc[NN_ + n]     + dist_b[n];
    float bb = acc[2 * NN_ + n] + bnd_b[n];
    dd = dd * sigm(m);
    bb = bb * sigm(dd);
    dd = dd + sigm(bb);
    float s = m + sigm(dd);
    float e = __expf(s);
    e_ws[((size_t)(b * NN_ + n) << 14) + p] = e;
    float t = e;
#pragma unroll
    for (int off = 32; off > 0; off >>= 1) t += __shfl_down(t, off, 64);
    if ((tid & 63) == 0) atomicAdd(&l_ws[b * NN_ + n], t);
  }
}

__global__ __launch_bounds__(256)
void k2_ocr(const float* __restrict__ x, float* __restrict__ ws) {
  __shared__ float xs[32][257];
  const int tid = threadIdx.x;
  const int pt = blockIdx.x, ct = blockIdx.y, b = blockIdx.z;
  const float* e_ws = ws + E_OFF;
  float acc[NN_];
#pragma unroll
  for (int n = 0; n < NN_; ++n) acc[n] = 0.f;
  const int cbase = ct * 256;
  const int p0 = pt * 1024;
  for (int pb = 0; pb < 1024; pb += 32) {
    const int pg = p0 + pb;
#pragma unroll
    for (int k = 0; k < 8; ++k) {
      int f = tid + k * 256;
      int cr = f >> 3, p4 = f & 7;
      const float4 v =
          *(const float4*)(x + (((size_t)(b * C_ + cbase + cr)) << 14) + pg + p4 * 4);
      xs[p4 * 4 + 0][cr] = v.x;
      xs[p4 * 4 + 1][cr] = v.y;
      xs[p4 * 4 + 2][cr] = v.z;
      xs[p4 * 4 + 3][cr] = v.w;
    }
    __syncthreads();
#pragma unroll 4
    for (int pp = 0; pp < 32; ++pp) {
      float xv = xs[pp][tid];
#pragma unroll
      for (int n = 0; n < NN_; ++n)
        acc[n] += e_ws[((size_t)(b * NN_ + n) << 14) + pg + pp] * xv;
    }
    __syncthreads();
  }
  float* ocr = ws + OCR_OFF;
#pragma unroll
  for (int n = 0; n < NN_; ++n)
    atomicAdd(&ocr[(b * NN_ + n) * C_ + cbase + tid], acc[n]);
}

__global__ __launch_bounds__(512)
void k4_out(const float* __restrict__ x, const float* __restrict__ fin_b,
            const float* __restrict__ ws, float* __restrict__ out) {
  __shared__ float wlds[C_ * 20];
  const int tid = threadIdx.x, b = blockIdx.y;
  const int p = blockIdx.x * 512 + tid;
  const float* fw = ws + FW_OFF + (size_t)b * NN_ * C_;
  for (int i = tid; i < NN_ * C_; i += 512) {
    int n = i >> 9, c = i & (C_ - 1);
    wlds[c * 20 + n] = fw[i];
  }
  __syncthreads();
  float acc[NN_];
#pragma unroll
  for (int n = 0; n < NN_; ++n) acc[n] = fin_b[n];
  const float* xp = x + ((size_t)b * C_) * HW_ + p;
  for (int c0 = 0; c0 < C_; c0 += 4) {
    float xv[4];
#pragma unroll
    for (int j = 0; j < 4; ++j) xv[j] = xp[(size_t)(c0 + j) * HW_];
#pragma unroll
    for (int j = 0; j < 4; ++j) {
      const float* wr = &wlds[(c0 + j) * 20];
#pragma unroll
      for (int n = 0; n < NN_; ++n) acc[n] += wr[n] * xv[j];
    }
  }
#pragma unroll
  for (int n = 0; n < NN_; ++n)
    out[((size_t)(b * NN_ + n) << 14) + p] = acc[n];
}

extern "C" void kernel_launch(void* const* d_in, const int* in_sizes, int n_in,
                              void* d_out, int out_size, void* d_ws, size_t ws_size,
                              hipStream_t stream) {
  const float* x      = (const float*)d_in[0];
  const float* map_w  = (const float*)d_in[1];
  const float* map_b  = (const float*)d_in[2];
  const float* dist_w = (const float*)d_in[3];
  const float* dist_b = (const float*)d_in[4];
  const float* bnd_w  = (const float*)d_in[5];
  const float* bnd_b  = (const float*)d_in[6];
  const float* mask_w = (const float*)d_in[7];
  const float* mask_b = (const float*)d_in[8];
  const float* cm1_w  = (const float*)d_in[9];
  const float* cm1_b  = (const float*)d_in[10];
  const float* ln_g   = (const float*)d_in[11];
  const float* ln_b   = (const float*)d_in[12];
  const float* cm2_w  = (const float*)d_in[13];
  const float* cm2_b  = (const float*)d_in[14];
  const float* fin_w  = (const float*)d_in[15];
  const float* fin_b  = (const float*)d_in[16];
  float* ws = (float*)d_ws;
  float* out = (float*)d_out;

  const bool fast = (ws_size >= FAST_WS_BYTES);  // constant per session: graph-safe

  if (fast) {
    int zw = 250112;
    k0_zero<<<dim3((zw + 255) / 256), dim3(256), 0, stream>>>(ws, zw);
    kp_packw<<<dim3(128), dim3(256), 0, stream>>>(map_w, dist_w, bnd_w, ws);
    kt_xT<<<dim3(256, 8, 8), dim3(256), 0, stream>>>(x, ws);
    k1_mfma<<<dim3(64, 8), dim3(256), 0, stream>>>(ws, map_b, dist_b, bnd_b, ws);
    k2_mfma<<<dim3(2, 32, 8), dim3(256), 0, stream>>>(x, ws, ws);
    k3a_ctx<<<dim3(8), dim3(256), 0, stream>>>(mask_w, mask_b, ws, 1);
    k3b_t1<<<dim3(8, 8), dim3(256), 0, stream>>>(cm1_w, cm1_b, ws);
    k3c_ln<<<dim3(8), dim3(512), 0, stream>>>(ln_g, ln_b, ws);
    k3d_gate<<<dim3(8, 8), dim3(256), 0, stream>>>(cm2_w, cm2_b, fin_w, ws, 1);
    k4_mfma<<<dim3(64, 8), dim3(256), 0, stream>>>(ws, fin_b, out);
  } else {
    int zw = 78080;
    k0_zero<<<dim3((zw + 255) / 256), dim3(256), 0, stream>>>(ws, zw);
    k1_scores<<<dim3(32, 8), dim3(512), 0, stream>>>(
        x, map_w, map_b, dist_w, dist_b, bnd_w, bnd_b, ws);
    k2_ocr<<<dim3(16, 2, 8), dim3(256), 0, stream>>>(x, ws);
    k3a_ctx<<<dim3(8), dim3(256), 0, stream>>>(mask_w, mask_b, ws, 0);
    k3b_t1<<<dim3(8, 8), dim3(256), 0, stream>>>(cm1_w, cm1_b, ws);
    k3c_ln<<<dim3(8), dim3(512), 0, stream>>>(ln_g, ln_b, ws);
    k3d_gate<<<dim3(8, 8), dim3(256), 0, stream>>>(cm2_w, cm2_b, fin_w, ws, 0);
    k4_out<<<dim3(32, 8), dim3(512), 0, stream>>>(x, fin_b, ws, out);
  }
}